// Round 1
// baseline (237.716 us; speedup 1.0000x reference)
//
#include <hip/hip_runtime.h>
#include <math.h>

// ---------------------------------------------------------------------------
// SelectiveAttention (no softmax!):
//   q  = query @ Wi + bi          [B,S,Dk]
//   kv = value @ Wi + bi          [B,S,Dk]
//   S_ij = (q_i . kv_j) * 1/sqrt(Dk)  masked to |i-j| <= band   (else 0)
//   att_i = sum_j S_ij kv_j       [B,S,Dk]
//   out = att @ Wo + bo           [B,S,D]
// B=4, S=4096, D=512, Dk=64, band=128.
// Round 1: correctness-first fp32 register-tiled implementation (3 kernels).
// ---------------------------------------------------------------------------

// y[M x 64] = x[M x K] @ Wi[K x 64] + bi ; z=0 -> query->qp, z=1 -> value->kvp
__global__ __launch_bounds__(256) void proj_in_kernel(
    const float* __restrict__ q, const float* __restrict__ v,
    const float* __restrict__ Wi, const float* __restrict__ bi,
    float* __restrict__ qp, float* __restrict__ kvp, int K)
{
    const float* x = blockIdx.z ? v : q;
    float* y = blockIdx.z ? kvp : qp;
    const int row0 = blockIdx.x * 64;

    __shared__ float As[64][33];   // [row][k]  (BK=32, +1 pad)
    __shared__ float Bs[32][65];   // [k][n]    (BN=64, +1 pad)

    const int tid = threadIdx.x;
    const int tx = tid & 15, ty = tid >> 4;

    float acc[4][4] = {};

    for (int k0 = 0; k0 < K; k0 += 32) {
        // As: 64x32 floats = 512 float4, 2 per thread
        #pragma unroll
        for (int i = 0; i < 2; i++) {
            int idx4 = tid * 2 + i;            // 0..511
            int r  = idx4 >> 3;                // 0..63
            int c4 = (idx4 & 7) * 4;           // 0..28
            const float4 f = *(const float4*)(x + (size_t)(row0 + r) * K + k0 + c4);
            As[r][c4 + 0] = f.x; As[r][c4 + 1] = f.y;
            As[r][c4 + 2] = f.z; As[r][c4 + 3] = f.w;
        }
        // Bs: 32x64 floats = 512 float4, 2 per thread
        #pragma unroll
        for (int i = 0; i < 2; i++) {
            int idx4 = tid * 2 + i;            // 0..511
            int r  = idx4 >> 4;                // 0..31
            int c4 = (idx4 & 15) * 4;          // 0..60
            const float4 f = *(const float4*)(Wi + (size_t)(k0 + r) * 64 + c4);
            Bs[r][c4 + 0] = f.x; Bs[r][c4 + 1] = f.y;
            Bs[r][c4 + 2] = f.z; Bs[r][c4 + 3] = f.w;
        }
        __syncthreads();

        #pragma unroll
        for (int k = 0; k < 32; k++) {
            float a[4], b[4];
            #pragma unroll
            for (int i = 0; i < 4; i++) a[i] = As[ty * 4 + i][k];
            #pragma unroll
            for (int j = 0; j < 4; j++) b[j] = Bs[k][tx * 4 + j];
            #pragma unroll
            for (int i = 0; i < 4; i++)
                #pragma unroll
                for (int j = 0; j < 4; j++)
                    acc[i][j] += a[i] * b[j];
        }
        __syncthreads();
    }

    #pragma unroll
    for (int i = 0; i < 4; i++) {
        int r = row0 + ty * 4 + i;
        #pragma unroll
        for (int j = 0; j < 4; j++) {
            int c = tx * 4 + j;
            y[(size_t)r * 64 + c] = acc[i][j] + bi[c];
        }
    }
}

// Banded scores + PV, one block per (batch, 64-query tile).
__global__ __launch_bounds__(256) void band_attn_kernel(
    const float* __restrict__ qp, const float* __restrict__ kvp,
    const int* __restrict__ band_ptr, float* __restrict__ att,
    int S, float scale)
{
    const int b  = blockIdx.y;
    const int q0 = blockIdx.x * 64;
    const int band = band_ptr[0];

    __shared__ float Qs[64][65];
    __shared__ float Ks[64][65];
    __shared__ float Ss[64][65];

    const int tid = threadIdx.x;
    const int tx = tid & 15, ty = tid >> 4;

    const float* qb = qp  + (size_t)b * S * 64;
    const float* kb = kvp + (size_t)b * S * 64;

    // load Q tile 64x64 (1024 float4, 4 per thread)
    #pragma unroll
    for (int i = 0; i < 4; i++) {
        int idx4 = tid * 4 + i;                // 0..1023
        int r  = idx4 >> 4;                    // 0..63
        int c4 = (idx4 & 15) * 4;              // 0..60
        const float4 f = *(const float4*)(qb + (size_t)(q0 + r) * 64 + c4);
        Qs[r][c4 + 0] = f.x; Qs[r][c4 + 1] = f.y;
        Qs[r][c4 + 2] = f.z; Qs[r][c4 + 3] = f.w;
    }

    float acc[4][4] = {};

    // key chunks covering [q0-band, q0+63+band]; >> is floor-div for negatives
    const int ch_lo = (q0 - band) >> 6;
    const int ch_hi = (q0 + 63 + band) >> 6;

    for (int ch = ch_lo; ch <= ch_hi; ch++) {
        const int k0 = ch * 64;
        // load K chunk (zero-padded outside [0,S))
        #pragma unroll
        for (int i = 0; i < 4; i++) {
            int idx4 = tid * 4 + i;
            int r  = idx4 >> 4;
            int c4 = (idx4 & 15) * 4;
            int kr = k0 + r;
            float4 f = make_float4(0.f, 0.f, 0.f, 0.f);
            if (kr >= 0 && kr < S)
                f = *(const float4*)(kb + (size_t)kr * 64 + c4);
            Ks[r][c4 + 0] = f.x; Ks[r][c4 + 1] = f.y;
            Ks[r][c4 + 2] = f.z; Ks[r][c4 + 3] = f.w;
        }
        __syncthreads();

        // scores: S = Q @ K^T (inner dim d = 64)
        float sc[4][4] = {};
        #pragma unroll
        for (int d = 0; d < 64; d++) {
            float a[4], bb[4];
            #pragma unroll
            for (int i = 0; i < 4; i++) a[i]  = Qs[ty * 4 + i][d];
            #pragma unroll
            for (int j = 0; j < 4; j++) bb[j] = Ks[tx * 4 + j][d];
            #pragma unroll
            for (int i = 0; i < 4; i++)
                #pragma unroll
                for (int j = 0; j < 4; j++)
                    sc[i][j] += a[i] * bb[j];
        }
        // mask to band, scale, stage in LDS
        #pragma unroll
        for (int i = 0; i < 4; i++) {
            int qi = q0 + ty * 4 + i;
            #pragma unroll
            for (int j = 0; j < 4; j++) {
                int kj = k0 + tx * 4 + j;
                int dlt = qi - kj; dlt = dlt < 0 ? -dlt : dlt;
                Ss[ty * 4 + i][tx * 4 + j] = (dlt <= band) ? sc[i][j] * scale : 0.f;
            }
        }
        __syncthreads();

        // att += S @ K  (inner dim = 64 keys)
        #pragma unroll
        for (int kk = 0; kk < 64; kk++) {
            float a[4], bb[4];
            #pragma unroll
            for (int i = 0; i < 4; i++) a[i]  = Ss[ty * 4 + i][kk];
            #pragma unroll
            for (int j = 0; j < 4; j++) bb[j] = Ks[kk][tx * 4 + j];
            #pragma unroll
            for (int i = 0; i < 4; i++)
                #pragma unroll
                for (int j = 0; j < 4; j++)
                    acc[i][j] += a[i] * bb[j];
        }
        __syncthreads();
    }

    #pragma unroll
    for (int i = 0; i < 4; i++) {
        int r = q0 + ty * 4 + i;
        #pragma unroll
        for (int j = 0; j < 4; j++)
            att[((size_t)b * S + r) * 64 + tx * 4 + j] = acc[i][j];
    }
}

// out[M x D] = att[M x 64] @ Wo[64 x D] + bo
__global__ __launch_bounds__(256) void proj_out_kernel(
    const float* __restrict__ att, const float* __restrict__ Wo,
    const float* __restrict__ bo, float* __restrict__ out, int D)
{
    const int row0 = blockIdx.x * 64;
    const int n0   = blockIdx.y * 64;

    __shared__ float As[64][65];   // att[row][k]
    __shared__ float Bs[64][65];   // Wo[k][n]

    const int tid = threadIdx.x;
    const int tx = tid & 15, ty = tid >> 4;

    #pragma unroll
    for (int i = 0; i < 4; i++) {
        int idx4 = tid * 4 + i;
        int r  = idx4 >> 4;
        int c4 = (idx4 & 15) * 4;
        const float4 f = *(const float4*)(att + (size_t)(row0 + r) * 64 + c4);
        As[r][c4 + 0] = f.x; As[r][c4 + 1] = f.y;
        As[r][c4 + 2] = f.z; As[r][c4 + 3] = f.w;
    }
    #pragma unroll
    for (int i = 0; i < 4; i++) {
        int idx4 = tid * 4 + i;
        int r  = idx4 >> 4;
        int c4 = (idx4 & 15) * 4;
        const float4 f = *(const float4*)(Wo + (size_t)r * D + n0 + c4);
        Bs[r][c4 + 0] = f.x; Bs[r][c4 + 1] = f.y;
        Bs[r][c4 + 2] = f.z; Bs[r][c4 + 3] = f.w;
    }
    __syncthreads();

    float acc[4][4] = {};
    #pragma unroll
    for (int k = 0; k < 64; k++) {
        float a[4], b[4];
        #pragma unroll
        for (int i = 0; i < 4; i++) a[i] = As[ty * 4 + i][k];
        #pragma unroll
        for (int j = 0; j < 4; j++) b[j] = Bs[k][tx * 4 + j];
        #pragma unroll
        for (int i = 0; i < 4; i++)
            #pragma unroll
            for (int j = 0; j < 4; j++)
                acc[i][j] += a[i] * b[j];
    }

    #pragma unroll
    for (int i = 0; i < 4; i++) {
        int r = row0 + ty * 4 + i;
        #pragma unroll
        for (int j = 0; j < 4; j++) {
            int c = n0 + tx * 4 + j;
            out[(size_t)r * D + c] = acc[i][j] + bo[c];
        }
    }
}

extern "C" void kernel_launch(void* const* d_in, const int* in_sizes, int n_in,
                              void* d_out, int out_size, void* d_ws, size_t ws_size,
                              hipStream_t stream) {
    const float* query = (const float*)d_in[0];
    const float* value = (const float*)d_in[1];
    const float* Wi    = (const float*)d_in[2];
    const float* bi    = (const float*)d_in[3];
    const float* Wo    = (const float*)d_in[4];
    const float* bo    = (const float*)d_in[5];
    const int*   band  = (const int*)d_in[6];
    float* out = (float*)d_out;

    const int Dk = in_sizes[3];            // 64
    const int D  = in_sizes[5];            // 512
    const int S  = 4096;                   // fixed by the benchmark
    const int BS = in_sizes[0] / D;        // B*S = 16384
    const int B  = BS / S;                 // 4
    const float scale = 1.0f / sqrtf((float)Dk);

    float* qp  = (float*)d_ws;                       // [BS, Dk]
    float* kvp = qp  + (size_t)BS * Dk;              // [BS, Dk]
    float* att = kvp + (size_t)BS * Dk;              // [BS, Dk]

    proj_in_kernel<<<dim3(BS / 64, 1, 2), 256, 0, stream>>>(
        query, value, Wi, bi, qp, kvp, D);

    band_attn_kernel<<<dim3(S / 64, B), 256, 0, stream>>>(
        qp, kvp, band, att, S, scale);

    proj_out_kernel<<<dim3(BS / 64, D / 64), 256, 0, stream>>>(
        att, Wo, bo, out, D);
}

// Round 2
// 158.761 us; speedup vs baseline: 1.4973x; 1.4973x over previous
//
#include <hip/hip_runtime.h>
#include <math.h>

// ---------------------------------------------------------------------------
// SelectiveAttention, bf16-MFMA pipeline (no softmax):
//   q  = query @ Wi + bi ; kv = value @ Wi + bi     [B,S,64]
//   S_ij = (q_i . kv_j)/8  masked to |i-j|<=128, else 0
//   att = S @ kv ; out = att @ Wo + bo              [B,S,512]
// B=4, S=4096, D=512, Dk=64, band=128.
//
// MFMA 16x16x32 bf16 fragment layouts (guide §3, m89/m120-verified):
//   A-frag: lane l holds A[m=l&15][k=(l>>4)*8+j], j=0..7  (16B contiguous)
//   B-frag: lane l holds B[k=(l>>4)*8+j][n=l&15]          (needs B^T storage)
//   C/D:    lane l, reg r -> C[row=(l>>4)*4+r][col=l&15]
// All B operands are pre-transposed (WiT, WoT, kvT) so every fragment load is
// a contiguous 16B read. band_attn is barrier-free: the S C->A layout
// round-trip uses a per-wave private LDS strip (same-wave write->read).
// ---------------------------------------------------------------------------

typedef __bf16 bf16;
using bf16x8  = __attribute__((ext_vector_type(8))) __bf16;
using floatx4 = __attribute__((ext_vector_type(4))) float;

#define MFMA(a, b, c) __builtin_amdgcn_mfma_f32_16x16x32_bf16(a, b, c, 0, 0, 0)

// WiT[n][k] = Wi[k][n] (64x512), WoT[n][k] = Wo[k][n] (512x64), both bf16.
__global__ __launch_bounds__(256) void prep_weights(
    const float* __restrict__ Wi, const float* __restrict__ Wo,
    bf16* __restrict__ WiT, bf16* __restrict__ WoT)
{
    const int idx = blockIdx.x * 256 + threadIdx.x;   // 0..32767
    {
        int n = idx >> 9, k = idx & 511;              // WiT: [64][512]
        WiT[idx] = (bf16)Wi[k * 64 + n];
    }
    {
        int n = idx >> 6, k = idx & 63;               // WoT: [512][64]
        WoT[idx] = (bf16)Wo[k * 512 + n];
    }
}

// y[M x 64] = x[M x K] @ Wi + bi, stored bf16. One wave = 16 rows x 64 cols.
__global__ __launch_bounds__(256, 4) void proj_in_kernel(
    const float* __restrict__ q, const float* __restrict__ v,
    const bf16* __restrict__ WiT, const float* __restrict__ bi,
    bf16* __restrict__ qp, bf16* __restrict__ kvp, int K)
{
    const float* x = blockIdx.z ? v : q;
    bf16* y = blockIdx.z ? kvp : qp;
    const int tid = threadIdx.x;
    const int wave = tid >> 6, lane = tid & 63;
    const int lr = lane & 15, lq = lane >> 4;
    const int row0 = (blockIdx.x * 4 + wave) * 16;
    const float* xrow = x + (size_t)(row0 + lr) * K;

    floatx4 acc[4] = {};
    #pragma unroll
    for (int ks = 0; ks < 16; ks++) {                 // K=512, 32 per MFMA
        const int k0 = ks * 32 + lq * 8;
        float4 a0 = *(const float4*)(xrow + k0);
        float4 a1 = *(const float4*)(xrow + k0 + 4);
        bf16x8 af;
        af[0] = (bf16)a0.x; af[1] = (bf16)a0.y; af[2] = (bf16)a0.z; af[3] = (bf16)a0.w;
        af[4] = (bf16)a1.x; af[5] = (bf16)a1.y; af[6] = (bf16)a1.z; af[7] = (bf16)a1.w;
        #pragma unroll
        for (int t = 0; t < 4; t++) {
            bf16x8 bf = *(const bf16x8*)(WiT + (size_t)(t * 16 + lr) * K + k0);
            acc[t] = MFMA(af, bf, acc[t]);
        }
    }
    #pragma unroll
    for (int t = 0; t < 4; t++) {
        float b = bi[t * 16 + lr];
        #pragma unroll
        for (int r = 0; r < 4; r++)
            y[(size_t)(row0 + lq * 4 + r) * 64 + t * 16 + lr] = (bf16)(acc[t][r] + b);
    }
}

// kvT[b][d][s] = kvp[b*S+s][d], bf16. 64x64 tile per block via LDS.
__global__ __launch_bounds__(256) void transpose_kv(
    const bf16* __restrict__ kvp, bf16* __restrict__ kvT, int S)
{
    const int b = blockIdx.y, s0 = blockIdx.x * 64;
    __shared__ bf16 L[64][88];                        // [d][s], pad 88 (16B-aligned rows)
    const int tid = threadIdx.x;
    #pragma unroll
    for (int i = 0; i < 2; i++) {
        int seg = tid * 2 + i;                        // 0..511
        int s = seg >> 3, d0 = (seg & 7) * 8;
        bf16x8 vv = *(const bf16x8*)(kvp + ((size_t)b * S + s0 + s) * 64 + d0);
        #pragma unroll
        for (int j = 0; j < 8; j++) L[d0 + j][s] = vv[j];
    }
    __syncthreads();
    #pragma unroll
    for (int i = 0; i < 2; i++) {
        int seg = tid * 2 + i;
        int d = seg >> 3, so = (seg & 7) * 8;
        bf16x8 vv;
        #pragma unroll
        for (int j = 0; j < 8; j++) vv[j] = L[d][so + j];
        *(bf16x8*)(kvT + ((size_t)b * 64 + d) * S + s0 + so) = vv;
    }
}

// Banded QK^T -> mask/scale -> PV. One wave = 16 queries, barrier-free.
__global__ __launch_bounds__(256, 4) void band_attn_kernel(
    const bf16* __restrict__ qp, const bf16* __restrict__ kvp,
    const bf16* __restrict__ kvT, const int* __restrict__ band_ptr,
    float* __restrict__ att, int S, float scale)
{
    __shared__ bf16 Ss[4][16][88];                    // per-wave private strip
    const int tid = threadIdx.x;
    const int wave = tid >> 6, lane = tid & 63;
    const int lr = lane & 15, lq = lane >> 4;
    const int gw = blockIdx.x * 4 + wave;             // global wave id
    const int b = gw >> 8;                            // 256 strips per batch
    const int q0 = (gw & 255) * 16;
    const int band = band_ptr[0];

    const bf16* qb = qp + ((size_t)b * S + q0) * 64;
    bf16x8 qf0 = *(const bf16x8*)(qb + lr * 64 + lq * 8);
    bf16x8 qf1 = *(const bf16x8*)(qb + lr * 64 + 32 + lq * 8);

    floatx4 acc[4] = {};
    const int ch_lo = (q0 - band) >> 6;               // floor-div
    const int ch_hi = (q0 + 15 + band) >> 6;
    for (int ch = ch_lo; ch <= ch_hi; ch++) {
        const int kj0 = ch * 64;
        // --- scores: S = Q @ K^T (k-dim = d = 64) ---
        floatx4 sc[4] = {};
        #pragma unroll
        for (int t = 0; t < 4; t++) {
            int kr = kj0 + t * 16 + lr;
            int krc = min(max(kr, 0), S - 1);         // clamp; masked below
            const bf16* kp = kvp + ((size_t)b * S + krc) * 64;
            bf16x8 b0 = *(const bf16x8*)(kp + lq * 8);
            bf16x8 b1 = *(const bf16x8*)(kp + 32 + lq * 8);
            sc[t] = MFMA(qf0, b0, sc[t]);
            sc[t] = MFMA(qf1, b1, sc[t]);
        }
        // --- mask+scale, C-layout -> A-layout via own LDS strip ---
        #pragma unroll
        for (int t = 0; t < 4; t++) {
            int kj = kj0 + t * 16 + lr;
            bool kv_ok = (kj >= 0) && (kj < S);
            #pragma unroll
            for (int r = 0; r < 4; r++) {
                int qi = q0 + lq * 4 + r;
                int dlt = qi - kj; dlt = dlt < 0 ? -dlt : dlt;
                float vv = (kv_ok && dlt <= band) ? sc[t][r] * scale : 0.f;
                Ss[wave][lq * 4 + r][t * 16 + lr] = (bf16)vv;
            }
        }
        // same-wave LDS write->read: ordered by lgkmcnt, no barrier needed
        // --- att += S @ K (k-dim = 64 keys) ---
        #pragma unroll
        for (int ks = 0; ks < 2; ks++) {
            bf16x8 sa = *(const bf16x8*)(&Ss[wave][lr][ks * 32 + lq * 8]);
            int kb = kj0 + ks * 32 + lq * 8;          // 8-aligned segment
            int kbc = min(max(kb, 0), S - 8);         // clamp; S-entries are 0 there
            #pragma unroll
            for (int t = 0; t < 4; t++) {
                bf16x8 vb = *(const bf16x8*)(kvT + ((size_t)b * 64 + t * 16 + lr) * S + kbc);
                acc[t] = MFMA(sa, vb, acc[t]);
            }
        }
    }
    #pragma unroll
    for (int t = 0; t < 4; t++)
        #pragma unroll
        for (int r = 0; r < 4; r++)
            att[((size_t)b * S + q0 + lq * 4 + r) * 64 + t * 16 + lr] = acc[t][r];
}

// out[M x D] = att[M x 64] @ Wo + bo. One wave = 16 rows x 128 cols.
__global__ __launch_bounds__(256, 4) void proj_out_kernel(
    const float* __restrict__ att, const bf16* __restrict__ WoT,
    const float* __restrict__ bo, float* __restrict__ out, int D)
{
    const int tid = threadIdx.x;
    const int wave = tid >> 6, lane = tid & 63;
    const int lr = lane & 15, lq = lane >> 4;
    const int row0 = blockIdx.x * 64 + wave * 16;
    const int n0 = blockIdx.y * 128;
    const float* ar = att + (size_t)(row0 + lr) * 64;

    bf16x8 af[2];
    #pragma unroll
    for (int ks = 0; ks < 2; ks++) {
        float4 a0 = *(const float4*)(ar + ks * 32 + lq * 8);
        float4 a1 = *(const float4*)(ar + ks * 32 + lq * 8 + 4);
        af[ks][0] = (bf16)a0.x; af[ks][1] = (bf16)a0.y;
        af[ks][2] = (bf16)a0.z; af[ks][3] = (bf16)a0.w;
        af[ks][4] = (bf16)a1.x; af[ks][5] = (bf16)a1.y;
        af[ks][6] = (bf16)a1.z; af[ks][7] = (bf16)a1.w;
    }
    floatx4 acc[8] = {};
    #pragma unroll
    for (int t = 0; t < 8; t++) {
        #pragma unroll
        for (int ks = 0; ks < 2; ks++) {
            bf16x8 bf = *(const bf16x8*)(WoT + (size_t)(n0 + t * 16 + lr) * 64 + ks * 32 + lq * 8);
            acc[t] = MFMA(af[ks], bf, acc[t]);
        }
    }
    #pragma unroll
    for (int t = 0; t < 8; t++) {
        float b = bo[n0 + t * 16 + lr];
        #pragma unroll
        for (int r = 0; r < 4; r++)
            out[(size_t)(row0 + lq * 4 + r) * D + n0 + t * 16 + lr] = acc[t][r] + b;
    }
}

extern "C" void kernel_launch(void* const* d_in, const int* in_sizes, int n_in,
                              void* d_out, int out_size, void* d_ws, size_t ws_size,
                              hipStream_t stream) {
    const float* query = (const float*)d_in[0];
    const float* value = (const float*)d_in[1];
    const float* Wi    = (const float*)d_in[2];
    const float* bi    = (const float*)d_in[3];
    const float* Wo    = (const float*)d_in[4];
    const float* bo    = (const float*)d_in[5];
    const int*   band  = (const int*)d_in[6];
    float* out = (float*)d_out;

    const int Dk = in_sizes[3];            // 64
    const int D  = in_sizes[5];            // 512
    const int S  = 4096;                   // fixed by the benchmark
    const int BS = in_sizes[0] / D;        // 16384
    const int B  = BS / S;                 // 4
    const float scale = 1.0f / sqrtf((float)Dk);

    // ws layout (bf16 then fp32): WiT 32K, WoT 32K, qp/kvp/kvT BS*64 each,
    // att BS*64 fp32. Total ~10.1 MB.
    bf16* WiT = (bf16*)d_ws;
    bf16* WoT = WiT + 32768;
    bf16* qp  = WoT + 32768;
    bf16* kvp = qp  + (size_t)BS * 64;
    bf16* kvT = kvp + (size_t)BS * 64;
    float* attb = (float*)(kvT + (size_t)BS * 64);

    prep_weights<<<128, 256, 0, stream>>>(Wi, Wo, WiT, WoT);

    proj_in_kernel<<<dim3(BS / 64, 1, 2), 256, 0, stream>>>(
        query, value, WiT, bi, qp, kvp, D);

    transpose_kv<<<dim3(S / 64, B), 256, 0, stream>>>(kvp, kvT, S);

    band_attn_kernel<<<dim3(BS / 64), 256, 0, stream>>>(
        qp, kvp, kvT, band, attb, S, scale);

    proj_out_kernel<<<dim3(BS / 64, D / 128), 256, 0, stream>>>(
        attb, WoT, bo, out, D);
}

// Round 3
// 158.294 us; speedup vs baseline: 1.5017x; 1.0030x over previous
//
#include <hip/hip_runtime.h>
#include <math.h>

// ---------------------------------------------------------------------------
// SelectiveAttention, bf16-MFMA pipeline (no softmax):
//   q  = query @ Wi + bi ; kv = value @ Wi + bi     [B,S,64]
//   S_ij = (q_i . kv_j)/8  masked to |i-j|<=128, else 0
//   att = S @ kv ; out = att @ Wo + bo              [B,S,512]
// B=4, S=4096, D=512, Dk=64, band=128.
//
// R3 changes vs R2 (158.8 us):
//  - prep_weights: LDS-tiled transpose (R2 did stride-256B fp32 gathers).
//  - band_attn: ping-pong S strips + full 5-chunk unroll for ILP (kernel is
//    grid-limited to 1 wave/SIMD, so ILP is the only latency hiding).
//  - transpose_kv: LDS pad 88->66 (odd word stride kills 4-way write conflict).
// ---------------------------------------------------------------------------

typedef __bf16 bf16;
using bf16x8  = __attribute__((ext_vector_type(8))) __bf16;
using floatx4 = __attribute__((ext_vector_type(4))) float;

#define MFMA(a, b, c) __builtin_amdgcn_mfma_f32_16x16x32_bf16(a, b, c, 0, 0, 0)

// WiT[n][k]=Wi[k][n] (64x512 bf16), WoT[n][k]=Wo[k][n] (512x64 bf16).
// Coalesced read -> LDS fp32 tile -> coalesced bf16x8 write.
__global__ __launch_bounds__(256) void prep_weights(
    const float* __restrict__ Wi, const float* __restrict__ Wo,
    bf16* __restrict__ WiT, bf16* __restrict__ WoT)
{
    __shared__ float T[64][65];
    const int blk = blockIdx.x, tid = threadIdx.x;
    if (blk < 8) {
        const int k0 = blk * 64;                      // Wi tile rows k0..k0+63
        #pragma unroll
        for (int i = 0; i < 4; i++) {
            int idx4 = tid * 4 + i;                   // 0..1023
            int r = idx4 >> 4, c4 = (idx4 & 15) * 4;
            float4 f = *(const float4*)(Wi + (size_t)(k0 + r) * 64 + c4);
            T[r][c4 + 0] = f.x; T[r][c4 + 1] = f.y;
            T[r][c4 + 2] = f.z; T[r][c4 + 3] = f.w;
        }
        __syncthreads();
        #pragma unroll
        for (int i = 0; i < 2; i++) {
            int seg = tid * 2 + i;                    // 0..511
            int n = seg >> 3, k8 = (seg & 7) * 8;
            bf16x8 v;
            #pragma unroll
            for (int j = 0; j < 8; j++) v[j] = (bf16)T[k8 + j][n];
            *(bf16x8*)(WiT + (size_t)n * 512 + k0 + k8) = v;
        }
    } else {
        const int n0 = (blk - 8) * 64;                // Wo tile cols n0..n0+63
        #pragma unroll
        for (int i = 0; i < 4; i++) {
            int idx4 = tid * 4 + i;
            int r = idx4 >> 4, c4 = (idx4 & 15) * 4;
            float4 f = *(const float4*)(Wo + (size_t)r * 512 + n0 + c4);
            T[r][c4 + 0] = f.x; T[r][c4 + 1] = f.y;
            T[r][c4 + 2] = f.z; T[r][c4 + 3] = f.w;
        }
        __syncthreads();
        #pragma unroll
        for (int i = 0; i < 2; i++) {
            int seg = tid * 2 + i;
            int n = seg >> 3, k8 = (seg & 7) * 8;
            bf16x8 v;
            #pragma unroll
            for (int j = 0; j < 8; j++) v[j] = (bf16)T[k8 + j][n];
            *(bf16x8*)(WoT + (size_t)(n0 + n) * 64 + k8) = v;
        }
    }
}

// y[M x 64] = x[M x K] @ Wi + bi, stored bf16. One wave = 16 rows x 64 cols.
__global__ __launch_bounds__(256, 2) void proj_in_kernel(
    const float* __restrict__ q, const float* __restrict__ v,
    const bf16* __restrict__ WiT, const float* __restrict__ bi,
    bf16* __restrict__ qp, bf16* __restrict__ kvp, int K)
{
    const float* x = blockIdx.z ? v : q;
    bf16* y = blockIdx.z ? kvp : qp;
    const int tid = threadIdx.x;
    const int wave = tid >> 6, lane = tid & 63;
    const int lr = lane & 15, lq = lane >> 4;
    const int row0 = (blockIdx.x * 4 + wave) * 16;
    const float* xrow = x + (size_t)(row0 + lr) * K;

    floatx4 acc[4] = {};
    #pragma unroll
    for (int ks = 0; ks < 16; ks++) {                 // K=512, 32 per MFMA
        const int k0 = ks * 32 + lq * 8;
        float4 a0 = *(const float4*)(xrow + k0);
        float4 a1 = *(const float4*)(xrow + k0 + 4);
        bf16x8 af;
        af[0] = (bf16)a0.x; af[1] = (bf16)a0.y; af[2] = (bf16)a0.z; af[3] = (bf16)a0.w;
        af[4] = (bf16)a1.x; af[5] = (bf16)a1.y; af[6] = (bf16)a1.z; af[7] = (bf16)a1.w;
        #pragma unroll
        for (int t = 0; t < 4; t++) {
            bf16x8 bf = *(const bf16x8*)(WiT + (size_t)(t * 16 + lr) * K + k0);
            acc[t] = MFMA(af, bf, acc[t]);
        }
    }
    #pragma unroll
    for (int t = 0; t < 4; t++) {
        float b = bi[t * 16 + lr];
        #pragma unroll
        for (int r = 0; r < 4; r++)
            y[(size_t)(row0 + lq * 4 + r) * 64 + t * 16 + lr] = (bf16)(acc[t][r] + b);
    }
}

// kvT[b][d][s] = kvp[b*S+s][d], bf16. 64x64 tile per block via LDS.
__global__ __launch_bounds__(256) void transpose_kv(
    const bf16* __restrict__ kvp, bf16* __restrict__ kvT, int S)
{
    const int b = blockIdx.y, s0 = blockIdx.x * 64;
    __shared__ bf16 L[64][66];       // stride 33 words (odd) -> <=2-way conflicts
    const int tid = threadIdx.x;
    #pragma unroll
    for (int i = 0; i < 2; i++) {
        int seg = tid * 2 + i;                        // 0..511
        int s = seg >> 3, d0 = (seg & 7) * 8;
        bf16x8 vv = *(const bf16x8*)(kvp + ((size_t)b * S + s0 + s) * 64 + d0);
        #pragma unroll
        for (int j = 0; j < 8; j++) L[d0 + j][s] = vv[j];
    }
    __syncthreads();
    #pragma unroll
    for (int i = 0; i < 2; i++) {
        int seg = tid * 2 + i;
        int d = seg >> 3, so = (seg & 7) * 8;
        bf16x8 vv;
        #pragma unroll
        for (int j = 0; j < 8; j++) vv[j] = L[d][so + j];
        *(bf16x8*)(kvT + ((size_t)b * 64 + d) * S + s0 + so) = vv;
    }
}

// Banded QK^T -> mask/scale -> PV. One wave = 16 queries, barrier-free.
// Grid-limited to ~1 wave/SIMD: ping-pong S strips + full unroll for ILP.
__global__ __launch_bounds__(256) void band_attn_kernel(
    const bf16* __restrict__ qp, const bf16* __restrict__ kvp,
    const bf16* __restrict__ kvT, const int* __restrict__ band_ptr,
    float* __restrict__ att, int S, float scale)
{
    __shared__ bf16 Ss[4][2][16][88];                 // [wave][pingpong][q][k]
    const int tid = threadIdx.x;
    const int wave = tid >> 6, lane = tid & 63;
    const int lr = lane & 15, lq = lane >> 4;
    const int gw = blockIdx.x * 4 + wave;             // global wave id
    const int b = gw >> 8;                            // 256 strips per batch
    const int q0 = (gw & 255) * 16;
    const int band = band_ptr[0];

    const bf16* qb = qp + ((size_t)b * S + q0) * 64;
    bf16x8 qf0 = *(const bf16x8*)(qb + lr * 64 + lq * 8);
    bf16x8 qf1 = *(const bf16x8*)(qb + lr * 64 + 32 + lq * 8);

    floatx4 acc[4] = {};
    const int ch_lo = (q0 - band) >> 6;               // floor-div; always 5 chunks
    #pragma unroll
    for (int cc = 0; cc < 5; cc++) {
        const int kj0 = (ch_lo + cc) * 64;
        bf16 (*strip)[88] = Ss[wave][cc & 1];
        // --- scores: S = Q @ K^T (k-dim = d = 64) ---
        floatx4 sc[4] = {};
        #pragma unroll
        for (int t = 0; t < 4; t++) {
            int kr = kj0 + t * 16 + lr;
            int krc = min(max(kr, 0), S - 1);         // clamp; masked below
            const bf16* kp = kvp + ((size_t)b * S + krc) * 64;
            bf16x8 b0 = *(const bf16x8*)(kp + lq * 8);
            bf16x8 b1 = *(const bf16x8*)(kp + 32 + lq * 8);
            sc[t] = MFMA(qf0, b0, sc[t]);
            sc[t] = MFMA(qf1, b1, sc[t]);
        }
        // --- mask+scale, C-layout -> A-layout via private strip ---
        #pragma unroll
        for (int t = 0; t < 4; t++) {
            int kj = kj0 + t * 16 + lr;
            bool kv_ok = (kj >= 0) && (kj < S);
            #pragma unroll
            for (int r = 0; r < 4; r++) {
                int qi = q0 + lq * 4 + r;
                int dlt = qi - kj; dlt = dlt < 0 ? -dlt : dlt;
                float vv = (kv_ok && dlt <= band) ? sc[t][r] * scale : 0.f;
                strip[lq * 4 + r][t * 16 + lr] = (bf16)vv;
            }
        }
        // same-wave LDS write->read: ordered by lgkmcnt, no barrier needed
        // --- att += S @ K (k-dim = 64 keys) ---
        #pragma unroll
        for (int ks = 0; ks < 2; ks++) {
            bf16x8 sa = *(const bf16x8*)(&strip[lr][ks * 32 + lq * 8]);
            int kb = kj0 + ks * 32 + lq * 8;          // 8-aligned segment
            int kbc = min(max(kb, 0), S - 8);         // clamp; S entries are 0 there
            #pragma unroll
            for (int t = 0; t < 4; t++) {
                bf16x8 vb = *(const bf16x8*)(kvT + ((size_t)b * 64 + t * 16 + lr) * S + kbc);
                acc[t] = MFMA(sa, vb, acc[t]);
            }
        }
    }
    #pragma unroll
    for (int t = 0; t < 4; t++)
        #pragma unroll
        for (int r = 0; r < 4; r++)
            att[((size_t)b * S + q0 + lq * 4 + r) * 64 + t * 16 + lr] = acc[t][r];
}

// out[M x D] = att[M x 64] @ Wo + bo. One wave = 16 rows x 128 cols.
__global__ __launch_bounds__(256, 4) void proj_out_kernel(
    const float* __restrict__ att, const bf16* __restrict__ WoT,
    const float* __restrict__ bo, float* __restrict__ out, int D)
{
    const int tid = threadIdx.x;
    const int wave = tid >> 6, lane = tid & 63;
    const int lr = lane & 15, lq = lane >> 4;
    const int row0 = blockIdx.x * 64 + wave * 16;
    const int n0 = blockIdx.y * 128;
    const float* ar = att + (size_t)(row0 + lr) * 64;

    bf16x8 af[2];
    #pragma unroll
    for (int ks = 0; ks < 2; ks++) {
        float4 a0 = *(const float4*)(ar + ks * 32 + lq * 8);
        float4 a1 = *(const float4*)(ar + ks * 32 + lq * 8 + 4);
        af[ks][0] = (bf16)a0.x; af[ks][1] = (bf16)a0.y;
        af[ks][2] = (bf16)a0.z; af[ks][3] = (bf16)a0.w;
        af[ks][4] = (bf16)a1.x; af[ks][5] = (bf16)a1.y;
        af[ks][6] = (bf16)a1.z; af[ks][7] = (bf16)a1.w;
    }
    floatx4 acc[8] = {};
    #pragma unroll
    for (int t = 0; t < 8; t++) {
        #pragma unroll
        for (int ks = 0; ks < 2; ks++) {
            bf16x8 bf = *(const bf16x8*)(WoT + (size_t)(n0 + t * 16 + lr) * 64 + ks * 32 + lq * 8);
            acc[t] = MFMA(af[ks], bf, acc[t]);
        }
    }
    #pragma unroll
    for (int t = 0; t < 8; t++) {
        float b = bo[n0 + t * 16 + lr];
        #pragma unroll
        for (int r = 0; r < 4; r++)
            out[(size_t)(row0 + lq * 4 + r) * D + n0 + t * 16 + lr] = acc[t][r] + b;
    }
}

extern "C" void kernel_launch(void* const* d_in, const int* in_sizes, int n_in,
                              void* d_out, int out_size, void* d_ws, size_t ws_size,
                              hipStream_t stream) {
    const float* query = (const float*)d_in[0];
    const float* value = (const float*)d_in[1];
    const float* Wi    = (const float*)d_in[2];
    const float* bi    = (const float*)d_in[3];
    const float* Wo    = (const float*)d_in[4];
    const float* bo    = (const float*)d_in[5];
    const int*   band  = (const int*)d_in[6];
    float* out = (float*)d_out;

    const int Dk = in_sizes[3];            // 64
    const int D  = in_sizes[5];            // 512
    const int S  = 4096;                   // fixed by the benchmark
    const int BS = in_sizes[0] / D;        // 16384
    const int B  = BS / S;                 // 4
    const float scale = 1.0f / sqrtf((float)Dk);

    bf16* WiT = (bf16*)d_ws;
    bf16* WoT = WiT + 32768;
    bf16* qp  = WoT + 32768;
    bf16* kvp = qp  + (size_t)BS * 64;
    bf16* kvT = kvp + (size_t)BS * 64;
    float* attb = (float*)(kvT + (size_t)BS * 64);

    prep_weights<<<16, 256, 0, stream>>>(Wi, Wo, WiT, WoT);

    proj_in_kernel<<<dim3(BS / 64, 1, 2), 256, 0, stream>>>(
        query, value, WiT, bi, qp, kvp, D);

    transpose_kv<<<dim3(S / 64, B), 256, 0, stream>>>(kvp, kvT, S);

    band_attn_kernel<<<dim3(BS / 64), 256, 0, stream>>>(
        qp, kvp, kvT, band, attb, S, scale);

    proj_out_kernel<<<dim3(BS / 64, D / 128), 256, 0, stream>>>(
        attb, WoT, bo, out, D);
}

// Round 4
// 150.896 us; speedup vs baseline: 1.5754x; 1.0490x over previous
//
#include <hip/hip_runtime.h>
#include <math.h>

// ---------------------------------------------------------------------------
// SelectiveAttention, bf16-MFMA, 3-kernel pipeline:
//   prep_weights:  Wi->WiT bf16, Wo->WoT bf16 (transposed for B-frags)
//   proj_in:       q/kv = x @ Wi + bi  (K-split x4 across waves + LDS reduce;
//                  kv branch also emits kvT[d][s] directly from the LDS tile)
//   band_attn_out: QK^T (banded, masked, scaled) -> PV -> @Wo + bo -> out
// B=4, S=4096, D=512, Dk=64, band=128.
//
// R4 rationale: timed loop contains ~100us of harness fill/restore (top-5 are
// fillBufferAligned @42us); our kernels are ~58us. proj_in was 2 waves/SIMD
// latency-limited on the mandatory 128MB fp32 read -> K-split raises it to
// 8 waves/SIMD. att never goes to HBM (fused epilogue). 5 -> 3 launches.
//
// MFMA 16x16x32 bf16 layouts (m89-verified):
//   A-frag: lane l holds A[m=l&15][k=(l>>4)*8+j]  (16B contiguous)
//   B-frag: lane l holds B[k=(l>>4)*8+j][n=l&15]  (B^T storage -> 16B reads)
//   C/D:    lane l, reg r -> C[row=(l>>4)*4+r][col=l&15]
// ---------------------------------------------------------------------------

typedef __bf16 bf16;
using bf16x4  = __attribute__((ext_vector_type(4))) __bf16;
using bf16x8  = __attribute__((ext_vector_type(8))) __bf16;
using floatx4 = __attribute__((ext_vector_type(4))) float;

#define MFMA(a, b, c) __builtin_amdgcn_mfma_f32_16x16x32_bf16(a, b, c, 0, 0, 0)

// WiT[n][k]=Wi[k][n] (64x512 bf16), WoT[n][k]=Wo[k][n] (512x64 bf16).
__global__ __launch_bounds__(256) void prep_weights(
    const float* __restrict__ Wi, const float* __restrict__ Wo,
    bf16* __restrict__ WiT, bf16* __restrict__ WoT)
{
    __shared__ float T[64][65];
    const int blk = blockIdx.x, tid = threadIdx.x;
    if (blk < 8) {
        const int k0 = blk * 64;
        #pragma unroll
        for (int i = 0; i < 4; i++) {
            int idx4 = tid * 4 + i;
            int r = idx4 >> 4, c4 = (idx4 & 15) * 4;
            float4 f = *(const float4*)(Wi + (size_t)(k0 + r) * 64 + c4);
            T[r][c4 + 0] = f.x; T[r][c4 + 1] = f.y;
            T[r][c4 + 2] = f.z; T[r][c4 + 3] = f.w;
        }
        __syncthreads();
        #pragma unroll
        for (int i = 0; i < 2; i++) {
            int seg = tid * 2 + i;
            int n = seg >> 3, k8 = (seg & 7) * 8;
            bf16x8 v;
            #pragma unroll
            for (int j = 0; j < 8; j++) v[j] = (bf16)T[k8 + j][n];
            *(bf16x8*)(WiT + (size_t)n * 512 + k0 + k8) = v;
        }
    } else {
        const int n0 = (blk - 8) * 64;
        #pragma unroll
        for (int i = 0; i < 4; i++) {
            int idx4 = tid * 4 + i;
            int r = idx4 >> 4, c4 = (idx4 & 15) * 4;
            float4 f = *(const float4*)(Wo + (size_t)r * 512 + n0 + c4);
            T[r][c4 + 0] = f.x; T[r][c4 + 1] = f.y;
            T[r][c4 + 2] = f.z; T[r][c4 + 3] = f.w;
        }
        __syncthreads();
        #pragma unroll
        for (int i = 0; i < 2; i++) {
            int seg = tid * 2 + i;
            int n = seg >> 3, k8 = (seg & 7) * 8;
            bf16x8 v;
            #pragma unroll
            for (int j = 0; j < 8; j++) v[j] = (bf16)T[k8 + j][n];
            *(bf16x8*)(WoT + (size_t)(n0 + n) * 64 + k8) = v;
        }
    }
}

// One block = 16 rows. Wave w covers k in [w*128, (w+1)*128). LDS fp32 reduce.
// z=0: query->qp. z=1: value->kvp AND kvT (transpose from the reduced tile).
__global__ __launch_bounds__(256) void proj_in_kernel(
    const float* __restrict__ q, const float* __restrict__ v,
    const bf16* __restrict__ WiT, const float* __restrict__ bi,
    bf16* __restrict__ qp, bf16* __restrict__ kvp, bf16* __restrict__ kvT,
    int K, int S)
{
    const float* x = blockIdx.z ? v : q;
    bf16* y = blockIdx.z ? kvp : qp;
    __shared__ float P[4][16][68];                    // [wave][row][col]
    const int tid = threadIdx.x;
    const int wave = tid >> 6, lane = tid & 63;
    const int lr = lane & 15, lq = lane >> 4;
    const int row0 = blockIdx.x * 16;
    const float* xrow = x + (size_t)(row0 + lr) * K + wave * 128;
    const bf16* wrow = WiT + wave * 128;

    floatx4 acc[4] = {};
    #pragma unroll
    for (int ks = 0; ks < 4; ks++) {
        const int k0 = ks * 32 + lq * 8;
        float4 a0 = *(const float4*)(xrow + k0);
        float4 a1 = *(const float4*)(xrow + k0 + 4);
        bf16x8 af;
        af[0] = (bf16)a0.x; af[1] = (bf16)a0.y; af[2] = (bf16)a0.z; af[3] = (bf16)a0.w;
        af[4] = (bf16)a1.x; af[5] = (bf16)a1.y; af[6] = (bf16)a1.z; af[7] = (bf16)a1.w;
        #pragma unroll
        for (int t = 0; t < 4; t++) {
            bf16x8 bfv = *(const bf16x8*)(wrow + (size_t)(t * 16 + lr) * K + k0);
            acc[t] = MFMA(af, bfv, acc[t]);
        }
    }
    #pragma unroll
    for (int t = 0; t < 4; t++)
        #pragma unroll
        for (int r = 0; r < 4; r++)
            P[wave][lq * 4 + r][t * 16 + lr] = acc[t][r];
    __syncthreads();

    {   // reduce + row-major write: thread -> (row, 4 cols)
        const int row = tid >> 4, c4 = (tid & 15) * 4;
        float4 s0 = *(const float4*)&P[0][row][c4];
        float4 s1 = *(const float4*)&P[1][row][c4];
        float4 s2 = *(const float4*)&P[2][row][c4];
        float4 s3 = *(const float4*)&P[3][row][c4];
        float4 bb = *(const float4*)(bi + c4);
        bf16x4 o;
        o[0] = (bf16)(s0.x + s1.x + s2.x + s3.x + bb.x);
        o[1] = (bf16)(s0.y + s1.y + s2.y + s3.y + bb.y);
        o[2] = (bf16)(s0.z + s1.z + s2.z + s3.z + bb.z);
        o[3] = (bf16)(s0.w + s1.w + s2.w + s3.w + bb.w);
        *(bf16x4*)(y + (size_t)(row0 + row) * 64 + c4) = o;
    }
    if (blockIdx.z) {                                 // kvT[d][s] transpose write
        const int d = tid >> 2, s4 = (tid & 3) * 4;
        const int b = row0 >> 12, s0r = row0 & (S - 1);
        const float bb = bi[d];
        bf16x4 o;
        #pragma unroll
        for (int i = 0; i < 4; i++) {
            float s = P[0][s4 + i][d] + P[1][s4 + i][d]
                    + P[2][s4 + i][d] + P[3][s4 + i][d] + bb;
            o[i] = (bf16)s;
        }
        *(bf16x4*)(kvT + ((size_t)b * 64 + d) * S + s0r + s4) = o;
    }
}

// Banded QK^T -> mask/scale -> PV -> (att @ Wo + bo) -> out. One wave = 16 q.
// Barrier-free: S/att C->A layout round-trips use a per-wave private strip.
__global__ __launch_bounds__(256) void band_attn_out_kernel(
    const bf16* __restrict__ qp, const bf16* __restrict__ kvp,
    const bf16* __restrict__ kvT, const int* __restrict__ band_ptr,
    const bf16* __restrict__ WoT, const float* __restrict__ bo,
    float* __restrict__ out, int S, float scale)
{
    __shared__ bf16 Ss[4][2][16][88];                 // [wave][pingpong][q][k]
    const int tid = threadIdx.x;
    const int wave = tid >> 6, lane = tid & 63;
    const int lr = lane & 15, lq = lane >> 4;
    const int gw = blockIdx.x * 4 + wave;
    const int b = gw >> 8;                            // 256 strips per batch
    const int q0 = (gw & 255) * 16;
    const int band = band_ptr[0];

    const bf16* qb = qp + ((size_t)b * S + q0) * 64;
    bf16x8 qf0 = *(const bf16x8*)(qb + lr * 64 + lq * 8);
    bf16x8 qf1 = *(const bf16x8*)(qb + lr * 64 + 32 + lq * 8);

    floatx4 acc[4] = {};
    const int ch_lo = (q0 - band) >> 6;               // band=128 -> 5 chunks
    #pragma unroll
    for (int cc = 0; cc < 5; cc++) {
        const int kj0 = (ch_lo + cc) * 64;
        bf16 (*strip)[88] = Ss[wave][cc & 1];
        floatx4 sc[4] = {};
        #pragma unroll
        for (int t = 0; t < 4; t++) {
            int kr = kj0 + t * 16 + lr;
            int krc = min(max(kr, 0), S - 1);         // clamp; masked below
            const bf16* kp = kvp + ((size_t)b * S + krc) * 64;
            bf16x8 b0 = *(const bf16x8*)(kp + lq * 8);
            bf16x8 b1 = *(const bf16x8*)(kp + 32 + lq * 8);
            sc[t] = MFMA(qf0, b0, sc[t]);
            sc[t] = MFMA(qf1, b1, sc[t]);
        }
        #pragma unroll
        for (int t = 0; t < 4; t++) {
            int kj = kj0 + t * 16 + lr;
            bool kv_ok = (kj >= 0) && (kj < S);
            #pragma unroll
            for (int r = 0; r < 4; r++) {
                int qi = q0 + lq * 4 + r;
                int dlt = qi - kj; dlt = dlt < 0 ? -dlt : dlt;
                float vv = (kv_ok && dlt <= band) ? sc[t][r] * scale : 0.f;
                strip[lq * 4 + r][t * 16 + lr] = (bf16)vv;
            }
        }
        // same-wave LDS write->read: in-order per wave, no barrier needed
        #pragma unroll
        for (int ks = 0; ks < 2; ks++) {
            bf16x8 sa = *(const bf16x8*)(&strip[lr][ks * 32 + lq * 8]);
            int kb = kj0 + ks * 32 + lq * 8;          // 8-aligned segment
            int kbc = min(max(kb, 0), S - 8);         // clamp; S entries are 0
            #pragma unroll
            for (int t = 0; t < 4; t++) {
                bf16x8 vb = *(const bf16x8*)(kvT + ((size_t)b * 64 + t * 16 + lr) * S + kbc);
                acc[t] = MFMA(sa, vb, acc[t]);
            }
        }
    }

    // ---- fused epilogue: out[16 x 512] = att @ Wo + bo ----
    bf16 (*strip)[88] = Ss[wave][0];                  // WAR on same wave: safe
    #pragma unroll
    for (int t = 0; t < 4; t++)
        #pragma unroll
        for (int r = 0; r < 4; r++)
            strip[lq * 4 + r][t * 16 + lr] = (bf16)acc[t][r];
    bf16x8 af0 = *(const bf16x8*)(&strip[lr][lq * 8]);
    bf16x8 af1 = *(const bf16x8*)(&strip[lr][32 + lq * 8]);
    float* orow = out + ((size_t)b * S + q0) * 512;
    #pragma unroll 8
    for (int tp = 0; tp < 32; tp++) {
        const bf16* wp = WoT + (size_t)(tp * 16 + lr) * 64;
        bf16x8 b0 = *(const bf16x8*)(wp + lq * 8);
        bf16x8 b1 = *(const bf16x8*)(wp + 32 + lq * 8);
        floatx4 o = {};
        o = MFMA(af0, b0, o);
        o = MFMA(af1, b1, o);
        float bb = bo[tp * 16 + lr];
        #pragma unroll
        for (int r = 0; r < 4; r++)
            orow[(size_t)(lq * 4 + r) * 512 + tp * 16 + lr] = o[r] + bb;
    }
}

extern "C" void kernel_launch(void* const* d_in, const int* in_sizes, int n_in,
                              void* d_out, int out_size, void* d_ws, size_t ws_size,
                              hipStream_t stream) {
    const float* query = (const float*)d_in[0];
    const float* value = (const float*)d_in[1];
    const float* Wi    = (const float*)d_in[2];
    const float* bi    = (const float*)d_in[3];
    const float* Wo    = (const float*)d_in[4];
    const float* bo    = (const float*)d_in[5];
    const int*   band  = (const int*)d_in[6];
    float* out = (float*)d_out;

    const int Dk = in_sizes[3];            // 64
    const int D  = in_sizes[5];            // 512
    const int S  = 4096;                   // fixed by the benchmark
    const int BS = in_sizes[0] / D;        // 16384
    const int B  = BS / S;                 // 4
    const float scale = 1.0f / sqrtf((float)Dk);

    bf16* WiT = (bf16*)d_ws;
    bf16* WoT = WiT + 32768;
    bf16* qp  = WoT + 32768;
    bf16* kvp = qp  + (size_t)BS * 64;
    bf16* kvT = kvp + (size_t)BS * 64;

    prep_weights<<<16, 256, 0, stream>>>(Wi, Wo, WiT, WoT);

    proj_in_kernel<<<dim3(BS / 16, 1, 2), 256, 0, stream>>>(
        query, value, WiT, bi, qp, kvp, kvT, D, S);

    band_attn_out_kernel<<<dim3(BS / 64), 256, 0, stream>>>(
        qp, kvp, kvT, band, WoT, bo, out, S, scale);
}

// Round 5
// 146.227 us; speedup vs baseline: 1.6257x; 1.0319x over previous
//
#include <hip/hip_runtime.h>
#include <math.h>

// ---------------------------------------------------------------------------
// SelectiveAttention, bf16-MFMA, 3-kernel pipeline:
//   prep_weights:  Wi->WiT bf16, Wo->WoT bf16 (transposed for B-frags)
//   proj_in:       q/kv = x @ Wi + bi (K-split x4 + LDS reduce; scale folded
//                  into qp; kv branch also emits kvT[d][s] from the LDS tile)
//   band_attn_out: QK^T (banded, masked) -> PV -> @Wo + bo -> out
// B=4, S=4096, D=512, Dk=64, band=128.
//
// R5: band_attn_out was 1 wave/SIMD (1024 waves total) -> split each 16-query
// strip across the block's 4 waves: chunks {w, w+4} per wave (private S-strip,
// barrier-free), acc reduced via LDS, epilogue n-dim split 4 ways. 4096 waves
// = 4 waves/SIMD. Timed loop still carries ~100us of harness fills.
//
// MFMA 16x16x32 bf16 layouts (m89-verified):
//   A-frag: lane l holds A[m=l&15][k=(l>>4)*8+j]  (16B contiguous)
//   B-frag: lane l holds B[k=(l>>4)*8+j][n=l&15]  (B^T storage -> 16B reads)
//   C/D:    lane l, reg r -> C[row=(l>>4)*4+r][col=l&15]
// ---------------------------------------------------------------------------

typedef __bf16 bf16;
using bf16x4  = __attribute__((ext_vector_type(4))) __bf16;
using bf16x8  = __attribute__((ext_vector_type(8))) __bf16;
using floatx4 = __attribute__((ext_vector_type(4))) float;

#define MFMA(a, b, c) __builtin_amdgcn_mfma_f32_16x16x32_bf16(a, b, c, 0, 0, 0)

// WiT[n][k]=Wi[k][n] (64x512 bf16), WoT[n][k]=Wo[k][n] (512x64 bf16).
__global__ __launch_bounds__(256) void prep_weights(
    const float* __restrict__ Wi, const float* __restrict__ Wo,
    bf16* __restrict__ WiT, bf16* __restrict__ WoT)
{
    __shared__ float T[64][65];
    const int blk = blockIdx.x, tid = threadIdx.x;
    if (blk < 8) {
        const int k0 = blk * 64;
        #pragma unroll
        for (int i = 0; i < 4; i++) {
            int idx4 = tid * 4 + i;
            int r = idx4 >> 4, c4 = (idx4 & 15) * 4;
            float4 f = *(const float4*)(Wi + (size_t)(k0 + r) * 64 + c4);
            T[r][c4 + 0] = f.x; T[r][c4 + 1] = f.y;
            T[r][c4 + 2] = f.z; T[r][c4 + 3] = f.w;
        }
        __syncthreads();
        #pragma unroll
        for (int i = 0; i < 2; i++) {
            int seg = tid * 2 + i;
            int n = seg >> 3, k8 = (seg & 7) * 8;
            bf16x8 v;
            #pragma unroll
            for (int j = 0; j < 8; j++) v[j] = (bf16)T[k8 + j][n];
            *(bf16x8*)(WiT + (size_t)n * 512 + k0 + k8) = v;
        }
    } else {
        const int n0 = (blk - 8) * 64;
        #pragma unroll
        for (int i = 0; i < 4; i++) {
            int idx4 = tid * 4 + i;
            int r = idx4 >> 4, c4 = (idx4 & 15) * 4;
            float4 f = *(const float4*)(Wo + (size_t)r * 512 + n0 + c4);
            T[r][c4 + 0] = f.x; T[r][c4 + 1] = f.y;
            T[r][c4 + 2] = f.z; T[r][c4 + 3] = f.w;
        }
        __syncthreads();
        #pragma unroll
        for (int i = 0; i < 2; i++) {
            int seg = tid * 2 + i;
            int n = seg >> 3, k8 = (seg & 7) * 8;
            bf16x8 v;
            #pragma unroll
            for (int j = 0; j < 8; j++) v[j] = (bf16)T[k8 + j][n];
            *(bf16x8*)(WoT + (size_t)(n0 + n) * 64 + k8) = v;
        }
    }
}

// One block = 16 rows. Wave w covers k in [w*128, (w+1)*128). LDS fp32 reduce.
// z=0: query -> qp (pre-scaled by 1/sqrt(Dk)). z=1: value -> kvp AND kvT.
__global__ __launch_bounds__(256) void proj_in_kernel(
    const float* __restrict__ q, const float* __restrict__ v,
    const bf16* __restrict__ WiT, const float* __restrict__ bi,
    bf16* __restrict__ qp, bf16* __restrict__ kvp, bf16* __restrict__ kvT,
    int K, int S, float scale)
{
    const float* x = blockIdx.z ? v : q;
    bf16* y = blockIdx.z ? kvp : qp;
    const float sc = blockIdx.z ? 1.0f : scale;
    __shared__ float P[4][16][68];                    // [wave][row][col]
    const int tid = threadIdx.x;
    const int wave = tid >> 6, lane = tid & 63;
    const int lr = lane & 15, lq = lane >> 4;
    const int row0 = blockIdx.x * 16;
    const float* xrow = x + (size_t)(row0 + lr) * K + wave * 128;
    const bf16* wrow = WiT + wave * 128;

    floatx4 acc[4] = {};
    #pragma unroll
    for (int ks = 0; ks < 4; ks++) {
        const int k0 = ks * 32 + lq * 8;
        float4 a0 = *(const float4*)(xrow + k0);
        float4 a1 = *(const float4*)(xrow + k0 + 4);
        bf16x8 af;
        af[0] = (bf16)a0.x; af[1] = (bf16)a0.y; af[2] = (bf16)a0.z; af[3] = (bf16)a0.w;
        af[4] = (bf16)a1.x; af[5] = (bf16)a1.y; af[6] = (bf16)a1.z; af[7] = (bf16)a1.w;
        #pragma unroll
        for (int t = 0; t < 4; t++) {
            bf16x8 bfv = *(const bf16x8*)(wrow + (size_t)(t * 16 + lr) * K + k0);
            acc[t] = MFMA(af, bfv, acc[t]);
        }
    }
    #pragma unroll
    for (int t = 0; t < 4; t++)
        #pragma unroll
        for (int r = 0; r < 4; r++)
            P[wave][lq * 4 + r][t * 16 + lr] = acc[t][r];
    __syncthreads();

    {   // reduce + row-major write
        const int row = tid >> 4, c4 = (tid & 15) * 4;
        float4 s0 = *(const float4*)&P[0][row][c4];
        float4 s1 = *(const float4*)&P[1][row][c4];
        float4 s2 = *(const float4*)&P[2][row][c4];
        float4 s3 = *(const float4*)&P[3][row][c4];
        float4 bb = *(const float4*)(bi + c4);
        bf16x4 o;
        o[0] = (bf16)((s0.x + s1.x + s2.x + s3.x + bb.x) * sc);
        o[1] = (bf16)((s0.y + s1.y + s2.y + s3.y + bb.y) * sc);
        o[2] = (bf16)((s0.z + s1.z + s2.z + s3.z + bb.z) * sc);
        o[3] = (bf16)((s0.w + s1.w + s2.w + s3.w + bb.w) * sc);
        *(bf16x4*)(y + (size_t)(row0 + row) * 64 + c4) = o;
    }
    if (blockIdx.z) {                                 // kvT[d][s] transpose write
        const int d = tid >> 2, s4 = (tid & 3) * 4;
        const int b = row0 >> 12, s0r = row0 & (S - 1);
        const float bb = bi[d];
        bf16x4 o;
        #pragma unroll
        for (int i = 0; i < 4; i++) {
            float s = P[0][s4 + i][d] + P[1][s4 + i][d]
                    + P[2][s4 + i][d] + P[3][s4 + i][d] + bb;
            o[i] = (bf16)s;
        }
        *(bf16x4*)(kvT + ((size_t)b * 64 + d) * S + s0r + s4) = o;
    }
}

// One block = one 16-query strip; 4 waves cooperate.
// Phase 1 (barrier-free per wave): wave w does band chunks {w, w+4}:
//   QK^T -> mask -> private S-strip -> PV partial acc.
// Phase 2: reduce acc via LDS -> shared bf16 A-strip.
// Phase 3: each wave does 8 of 32 n-tiles of att @ Wo + bo.
__global__ __launch_bounds__(256) void band_attn_out_kernel(
    const bf16* __restrict__ qp, const bf16* __restrict__ kvp,
    const bf16* __restrict__ kvT, const int* __restrict__ band_ptr,
    const bf16* __restrict__ WoT, const float* __restrict__ bo,
    float* __restrict__ out, int S)
{
    __shared__ bf16 Ss[4][16][88];                    // per-wave score strip
    __shared__ float P[4][16][68];                    // partial acc for reduce
    __shared__ bf16 St[16][72];                       // reduced att (A-layout src)
    const int tid = threadIdx.x;
    const int wave = tid >> 6, lane = tid & 63;
    const int lr = lane & 15, lq = lane >> 4;
    const int gs = blockIdx.x;                        // strip id
    const int b = gs >> 8;                            // 256 strips per batch
    const int q0 = (gs & 255) * 16;
    const int band = band_ptr[0];

    const bf16* qb = qp + ((size_t)b * S + q0) * 64;
    bf16x8 qf0 = *(const bf16x8*)(qb + lr * 64 + lq * 8);
    bf16x8 qf1 = *(const bf16x8*)(qb + lr * 64 + 32 + lq * 8);

    floatx4 acc[4] = {};
    const int ch_lo = (q0 - band) >> 6;               // band=128 -> 5 chunks
    #pragma unroll
    for (int pass = 0; pass < 2; pass++) {
        const int cc = wave + pass * 4;               // wave0: {0,4}; w: {w}
        if (cc <= 4) {
            const int kj0 = (ch_lo + cc) * 64;
            floatx4 sc[4] = {};
            #pragma unroll
            for (int t = 0; t < 4; t++) {
                int kr = kj0 + t * 16 + lr;
                int krc = min(max(kr, 0), S - 1);     // clamp; masked below
                const bf16* kp = kvp + ((size_t)b * S + krc) * 64;
                bf16x8 b0 = *(const bf16x8*)(kp + lq * 8);
                bf16x8 b1 = *(const bf16x8*)(kp + 32 + lq * 8);
                sc[t] = MFMA(qf0, b0, sc[t]);
                sc[t] = MFMA(qf1, b1, sc[t]);
            }
            #pragma unroll
            for (int t = 0; t < 4; t++) {
                int kj = kj0 + t * 16 + lr;
                bool kv_ok = (kj >= 0) && (kj < S);
                #pragma unroll
                for (int r = 0; r < 4; r++) {
                    int qi = q0 + lq * 4 + r;
                    int dlt = qi - kj; dlt = dlt < 0 ? -dlt : dlt;
                    float vv = (kv_ok && dlt <= band) ? sc[t][r] : 0.f;
                    Ss[wave][lq * 4 + r][t * 16 + lr] = (bf16)vv;
                }
            }
            // same-wave LDS write->read: in-order per wave, no barrier needed
            #pragma unroll
            for (int ks = 0; ks < 2; ks++) {
                bf16x8 sa = *(const bf16x8*)(&Ss[wave][lr][ks * 32 + lq * 8]);
                int kb = kj0 + ks * 32 + lq * 8;      // 8-aligned segment
                int kbc = min(max(kb, 0), S - 8);     // clamp; S entries are 0
                #pragma unroll
                for (int t = 0; t < 4; t++) {
                    bf16x8 vb = *(const bf16x8*)(kvT + ((size_t)b * 64 + t * 16 + lr) * S + kbc);
                    acc[t] = MFMA(sa, vb, acc[t]);
                }
            }
        }
    }
    #pragma unroll
    for (int t = 0; t < 4; t++)
        #pragma unroll
        for (int r = 0; r < 4; r++)
            P[wave][lq * 4 + r][t * 16 + lr] = acc[t][r];
    __syncthreads();

    {   // reduce 4 partials -> bf16 att strip
        const int row = tid >> 4, c4 = (tid & 15) * 4;
        float4 s0 = *(const float4*)&P[0][row][c4];
        float4 s1 = *(const float4*)&P[1][row][c4];
        float4 s2 = *(const float4*)&P[2][row][c4];
        float4 s3 = *(const float4*)&P[3][row][c4];
        bf16x4 o;
        o[0] = (bf16)(s0.x + s1.x + s2.x + s3.x);
        o[1] = (bf16)(s0.y + s1.y + s2.y + s3.y);
        o[2] = (bf16)(s0.z + s1.z + s2.z + s3.z);
        o[3] = (bf16)(s0.w + s1.w + s2.w + s3.w);
        *(bf16x4*)(&St[row][c4]) = o;
    }
    __syncthreads();

    // epilogue quarter per wave: n-tiles tp = wave*8 .. wave*8+7
    bf16x8 af0 = *(const bf16x8*)(&St[lr][lq * 8]);
    bf16x8 af1 = *(const bf16x8*)(&St[lr][32 + lq * 8]);
    float* orow = out + ((size_t)b * S + q0) * 512;
    #pragma unroll
    for (int i = 0; i < 8; i++) {
        const int tp = wave * 8 + i;
        const bf16* wp = WoT + (size_t)(tp * 16 + lr) * 64;
        bf16x8 b0 = *(const bf16x8*)(wp + lq * 8);
        bf16x8 b1 = *(const bf16x8*)(wp + 32 + lq * 8);
        floatx4 o = {};
        o = MFMA(af0, b0, o);
        o = MFMA(af1, b1, o);
        float bb = bo[tp * 16 + lr];
        #pragma unroll
        for (int r = 0; r < 4; r++)
            orow[(size_t)(lq * 4 + r) * 512 + tp * 16 + lr] = o[r] + bb;
    }
}

extern "C" void kernel_launch(void* const* d_in, const int* in_sizes, int n_in,
                              void* d_out, int out_size, void* d_ws, size_t ws_size,
                              hipStream_t stream) {
    const float* query = (const float*)d_in[0];
    const float* value = (const float*)d_in[1];
    const float* Wi    = (const float*)d_in[2];
    const float* bi    = (const float*)d_in[3];
    const float* Wo    = (const float*)d_in[4];
    const float* bo    = (const float*)d_in[5];
    const int*   band  = (const int*)d_in[6];
    float* out = (float*)d_out;

    const int Dk = in_sizes[3];            // 64
    const int D  = in_sizes[5];            // 512
    const int S  = 4096;                   // fixed by the benchmark
    const int BS = in_sizes[0] / D;        // 16384
    const int B  = BS / S;                 // 4
    const float scale = 1.0f / sqrtf((float)Dk);

    bf16* WiT = (bf16*)d_ws;
    bf16* WoT = WiT + 32768;
    bf16* qp  = WoT + 32768;
    bf16* kvp = qp  + (size_t)BS * 64;
    bf16* kvT = kvp + (size_t)BS * 64;

    prep_weights<<<16, 256, 0, stream>>>(Wi, Wo, WiT, WoT);

    proj_in_kernel<<<dim3(BS / 16, 1, 2), 256, 0, stream>>>(
        query, value, WiT, bi, qp, kvp, kvT, D, S, scale);

    band_attn_out_kernel<<<dim3(BS / 16), 256, 0, stream>>>(
        qp, kvp, kvT, band, WoT, bo, out, S);
}

// Round 6
// 145.820 us; speedup vs baseline: 1.6302x; 1.0028x over previous
//
#include <hip/hip_runtime.h>
#include <math.h>

// ---------------------------------------------------------------------------
// SelectiveAttention, bf16-MFMA, 3-kernel pipeline:
//   prep_weights:   Wi->WiT bf16, Wo->WoT bf16 (transposed for B-frags)
//   proj_in(value): kv = value @ Wi + bi -> kvp (row-major) + kvT (transposed)
//   band_attn_out:  q-proj (own strip, fused) -> banded QK^T -> mask -> PV
//                   -> @Wo + bo -> out
// B=4, S=4096, D=512, Dk=64, band=128.
//
// R6: query projection moved INTO band_attn_out (a 16-query strip only needs
// its own q rows -> no cross-block dep). proj_in halves; qp round-trip gone;
// the 64MB query read now overlaps band's MFMA work. Timed loop still carries
// ~100us of harness fill/restore (top-5 dispatches are fillBufferAligned).
//
// MFMA 16x16x32 bf16 layouts (m89-verified):
//   A-frag: lane l holds A[m=l&15][k=(l>>4)*8+j]  (16B contiguous)
//   B-frag: lane l holds B[k=(l>>4)*8+j][n=l&15]  (B^T storage -> 16B reads)
//   C/D:    lane l, reg r -> C[row=(l>>4)*4+r][col=l&15]
// ---------------------------------------------------------------------------

typedef __bf16 bf16;
using bf16x4  = __attribute__((ext_vector_type(4))) __bf16;
using bf16x8  = __attribute__((ext_vector_type(8))) __bf16;
using floatx4 = __attribute__((ext_vector_type(4))) float;

#define MFMA(a, b, c) __builtin_amdgcn_mfma_f32_16x16x32_bf16(a, b, c, 0, 0, 0)

// WiT[n][k]=Wi[k][n] (64x512 bf16), WoT[n][k]=Wo[k][n] (512x64 bf16).
__global__ __launch_bounds__(256) void prep_weights(
    const float* __restrict__ Wi, const float* __restrict__ Wo,
    bf16* __restrict__ WiT, bf16* __restrict__ WoT)
{
    __shared__ float T[64][65];
    const int blk = blockIdx.x, tid = threadIdx.x;
    if (blk < 8) {
        const int k0 = blk * 64;
        #pragma unroll
        for (int i = 0; i < 4; i++) {
            int idx4 = tid * 4 + i;
            int r = idx4 >> 4, c4 = (idx4 & 15) * 4;
            float4 f = *(const float4*)(Wi + (size_t)(k0 + r) * 64 + c4);
            T[r][c4 + 0] = f.x; T[r][c4 + 1] = f.y;
            T[r][c4 + 2] = f.z; T[r][c4 + 3] = f.w;
        }
        __syncthreads();
        #pragma unroll
        for (int i = 0; i < 2; i++) {
            int seg = tid * 2 + i;
            int n = seg >> 3, k8 = (seg & 7) * 8;
            bf16x8 v;
            #pragma unroll
            for (int j = 0; j < 8; j++) v[j] = (bf16)T[k8 + j][n];
            *(bf16x8*)(WiT + (size_t)n * 512 + k0 + k8) = v;
        }
    } else {
        const int n0 = (blk - 8) * 64;
        #pragma unroll
        for (int i = 0; i < 4; i++) {
            int idx4 = tid * 4 + i;
            int r = idx4 >> 4, c4 = (idx4 & 15) * 4;
            float4 f = *(const float4*)(Wo + (size_t)r * 512 + n0 + c4);
            T[r][c4 + 0] = f.x; T[r][c4 + 1] = f.y;
            T[r][c4 + 2] = f.z; T[r][c4 + 3] = f.w;
        }
        __syncthreads();
        #pragma unroll
        for (int i = 0; i < 2; i++) {
            int seg = tid * 2 + i;
            int n = seg >> 3, k8 = (seg & 7) * 8;
            bf16x8 v;
            #pragma unroll
            for (int j = 0; j < 8; j++) v[j] = (bf16)T[k8 + j][n];
            *(bf16x8*)(WoT + (size_t)(n0 + n) * 64 + k8) = v;
        }
    }
}

// One block = 16 rows of value. Wave w covers k in [w*128,(w+1)*128). LDS
// reduce -> kvp row-major + kvT[d][s] transposed.
__global__ __launch_bounds__(256) void proj_in_kernel(
    const float* __restrict__ v, const bf16* __restrict__ WiT,
    const float* __restrict__ bi, bf16* __restrict__ kvp,
    bf16* __restrict__ kvT, int K, int S)
{
    __shared__ float P[4][16][68];                    // [wave][row][col]
    const int tid = threadIdx.x;
    const int wave = tid >> 6, lane = tid & 63;
    const int lr = lane & 15, lq = lane >> 4;
    const int row0 = blockIdx.x * 16;
    const float* xrow = v + (size_t)(row0 + lr) * K + wave * 128;
    const bf16* wrow = WiT + wave * 128;

    floatx4 acc[4] = {};
    #pragma unroll
    for (int ks = 0; ks < 4; ks++) {
        const int k0 = ks * 32 + lq * 8;
        float4 a0 = *(const float4*)(xrow + k0);
        float4 a1 = *(const float4*)(xrow + k0 + 4);
        bf16x8 af;
        af[0] = (bf16)a0.x; af[1] = (bf16)a0.y; af[2] = (bf16)a0.z; af[3] = (bf16)a0.w;
        af[4] = (bf16)a1.x; af[5] = (bf16)a1.y; af[6] = (bf16)a1.z; af[7] = (bf16)a1.w;
        #pragma unroll
        for (int t = 0; t < 4; t++) {
            bf16x8 bfv = *(const bf16x8*)(wrow + (size_t)(t * 16 + lr) * K + k0);
            acc[t] = MFMA(af, bfv, acc[t]);
        }
    }
    #pragma unroll
    for (int t = 0; t < 4; t++)
        #pragma unroll
        for (int r = 0; r < 4; r++)
            P[wave][lq * 4 + r][t * 16 + lr] = acc[t][r];
    __syncthreads();

    {   // reduce + row-major write
        const int row = tid >> 4, c4 = (tid & 15) * 4;
        float4 s0 = *(const float4*)&P[0][row][c4];
        float4 s1 = *(const float4*)&P[1][row][c4];
        float4 s2 = *(const float4*)&P[2][row][c4];
        float4 s3 = *(const float4*)&P[3][row][c4];
        float4 bb = *(const float4*)(bi + c4);
        bf16x4 o;
        o[0] = (bf16)(s0.x + s1.x + s2.x + s3.x + bb.x);
        o[1] = (bf16)(s0.y + s1.y + s2.y + s3.y + bb.y);
        o[2] = (bf16)(s0.z + s1.z + s2.z + s3.z + bb.z);
        o[3] = (bf16)(s0.w + s1.w + s2.w + s3.w + bb.w);
        *(bf16x4*)(kvp + (size_t)(row0 + row) * 64 + c4) = o;
    }
    {   // kvT[d][s] transpose write
        const int d = tid >> 2, s4 = (tid & 3) * 4;
        const int b = row0 >> 12, s0r = row0 & (S - 1);
        const float bb = bi[d];
        bf16x4 o;
        #pragma unroll
        for (int i = 0; i < 4; i++) {
            float s = P[0][s4 + i][d] + P[1][s4 + i][d]
                    + P[2][s4 + i][d] + P[3][s4 + i][d] + bb;
            o[i] = (bf16)s;
        }
        *(bf16x4*)(kvT + ((size_t)b * 64 + d) * S + s0r + s4) = o;
    }
}

// One block = one 16-query strip; 4 waves cooperate.
// Phase 0: fused q-proj of own strip (K-split x4, LDS reduce, +bi, *scale).
// Phase 1 (barrier-free per wave): wave w does band chunks {w, w+4}:
//   QK^T -> mask -> private S-strip -> PV partial acc.
// Phase 2: reduce acc via LDS -> shared bf16 att strip.
// Phase 3: each wave does 8 of 32 n-tiles of att @ Wo + bo.
__global__ __launch_bounds__(256) void band_attn_out_kernel(
    const float* __restrict__ query, const bf16* __restrict__ WiT,
    const float* __restrict__ bi, const bf16* __restrict__ kvp,
    const bf16* __restrict__ kvT, const int* __restrict__ band_ptr,
    const bf16* __restrict__ WoT, const float* __restrict__ bo,
    float* __restrict__ out, int K, int S, float scale)
{
    __shared__ bf16 Ss[4][16][88];                    // per-wave score strip
    __shared__ float P[4][16][68];                    // partials (q-proj, acc)
    __shared__ bf16 St[16][88];                       // q strip / att strip
    const int tid = threadIdx.x;
    const int wave = tid >> 6, lane = tid & 63;
    const int lr = lane & 15, lq = lane >> 4;
    const int gs = blockIdx.x;                        // strip id
    const int b = gs >> 8;                            // 256 strips per batch
    const int q0 = (gs & 255) * 16;
    const int band = band_ptr[0];

    // ---- phase 0: q-proj of rows [b*S+q0, +16) ----
    {
        const float* xrow = query + ((size_t)b * S + q0 + lr) * K + wave * 128;
        const bf16* wrow = WiT + wave * 128;
        floatx4 qa[4] = {};
        #pragma unroll
        for (int ks = 0; ks < 4; ks++) {
            const int k0 = ks * 32 + lq * 8;
            float4 a0 = *(const float4*)(xrow + k0);
            float4 a1 = *(const float4*)(xrow + k0 + 4);
            bf16x8 af;
            af[0] = (bf16)a0.x; af[1] = (bf16)a0.y; af[2] = (bf16)a0.z; af[3] = (bf16)a0.w;
            af[4] = (bf16)a1.x; af[5] = (bf16)a1.y; af[6] = (bf16)a1.z; af[7] = (bf16)a1.w;
            #pragma unroll
            for (int t = 0; t < 4; t++) {
                bf16x8 bfv = *(const bf16x8*)(wrow + (size_t)(t * 16 + lr) * K + k0);
                qa[t] = MFMA(af, bfv, qa[t]);
            }
        }
        #pragma unroll
        for (int t = 0; t < 4; t++)
            #pragma unroll
            for (int r = 0; r < 4; r++)
                P[wave][lq * 4 + r][t * 16 + lr] = qa[t][r];
    }
    __syncthreads();
    {   // reduce + bias + scale -> bf16 q strip
        const int row = tid >> 4, c4 = (tid & 15) * 4;
        float4 s0 = *(const float4*)&P[0][row][c4];
        float4 s1 = *(const float4*)&P[1][row][c4];
        float4 s2 = *(const float4*)&P[2][row][c4];
        float4 s3 = *(const float4*)&P[3][row][c4];
        float4 bb = *(const float4*)(bi + c4);
        bf16x4 o;
        o[0] = (bf16)((s0.x + s1.x + s2.x + s3.x + bb.x) * scale);
        o[1] = (bf16)((s0.y + s1.y + s2.y + s3.y + bb.y) * scale);
        o[2] = (bf16)((s0.z + s1.z + s2.z + s3.z + bb.z) * scale);
        o[3] = (bf16)((s0.w + s1.w + s2.w + s3.w + bb.w) * scale);
        *(bf16x4*)(&St[row][c4]) = o;
    }
    __syncthreads();
    bf16x8 qf0 = *(const bf16x8*)(&St[lr][lq * 8]);
    bf16x8 qf1 = *(const bf16x8*)(&St[lr][32 + lq * 8]);

    // ---- phase 1: banded QK^T -> mask -> PV (chunks {wave, wave+4}) ----
    floatx4 acc[4] = {};
    const int ch_lo = (q0 - band) >> 6;               // band=128 -> 5 chunks
    #pragma unroll
    for (int pass = 0; pass < 2; pass++) {
        const int cc = wave + pass * 4;               // wave0: {0,4}; w: {w}
        if (cc <= 4) {
            const int kj0 = (ch_lo + cc) * 64;
            floatx4 sc[4] = {};
            #pragma unroll
            for (int t = 0; t < 4; t++) {
                int kr = kj0 + t * 16 + lr;
                int krc = min(max(kr, 0), S - 1);     // clamp; masked below
                const bf16* kp = kvp + ((size_t)b * S + krc) * 64;
                bf16x8 b0 = *(const bf16x8*)(kp + lq * 8);
                bf16x8 b1 = *(const bf16x8*)(kp + 32 + lq * 8);
                sc[t] = MFMA(qf0, b0, sc[t]);
                sc[t] = MFMA(qf1, b1, sc[t]);
            }
            #pragma unroll
            for (int t = 0; t < 4; t++) {
                int kj = kj0 + t * 16 + lr;
                bool kv_ok = (kj >= 0) && (kj < S);
                #pragma unroll
                for (int r = 0; r < 4; r++) {
                    int qi = q0 + lq * 4 + r;
                    int dlt = qi - kj; dlt = dlt < 0 ? -dlt : dlt;
                    float vv = (kv_ok && dlt <= band) ? sc[t][r] : 0.f;
                    Ss[wave][lq * 4 + r][t * 16 + lr] = (bf16)vv;
                }
            }
            // same-wave LDS write->read: in-order per wave, no barrier needed
            #pragma unroll
            for (int ks = 0; ks < 2; ks++) {
                bf16x8 sa = *(const bf16x8*)(&Ss[wave][lr][ks * 32 + lq * 8]);
                int kb = kj0 + ks * 32 + lq * 8;      // 8-aligned segment
                int kbc = min(max(kb, 0), S - 8);     // clamp; S entries are 0
                #pragma unroll
                for (int t = 0; t < 4; t++) {
                    bf16x8 vb = *(const bf16x8*)(kvT + ((size_t)b * 64 + t * 16 + lr) * S + kbc);
                    acc[t] = MFMA(sa, vb, acc[t]);
                }
            }
        }
    }
    #pragma unroll
    for (int t = 0; t < 4; t++)
        #pragma unroll
        for (int r = 0; r < 4; r++)
            P[wave][lq * 4 + r][t * 16 + lr] = acc[t][r];
    __syncthreads();

    // ---- phase 2: reduce 4 partials -> bf16 att strip ----
    {
        const int row = tid >> 4, c4 = (tid & 15) * 4;
        float4 s0 = *(const float4*)&P[0][row][c4];
        float4 s1 = *(const float4*)&P[1][row][c4];
        float4 s2 = *(const float4*)&P[2][row][c4];
        float4 s3 = *(const float4*)&P[3][row][c4];
        bf16x4 o;
        o[0] = (bf16)(s0.x + s1.x + s2.x + s3.x);
        o[1] = (bf16)(s0.y + s1.y + s2.y + s3.y);
        o[2] = (bf16)(s0.z + s1.z + s2.z + s3.z);
        o[3] = (bf16)(s0.w + s1.w + s2.w + s3.w);
        *(bf16x4*)(&St[row][c4]) = o;
    }
    __syncthreads();

    // ---- phase 3: epilogue quarter per wave: n-tiles wave*8 .. wave*8+7 ----
    bf16x8 af0 = *(const bf16x8*)(&St[lr][lq * 8]);
    bf16x8 af1 = *(const bf16x8*)(&St[lr][32 + lq * 8]);
    float* orow = out + ((size_t)b * S + q0) * 512;
    #pragma unroll
    for (int i = 0; i < 8; i++) {
        const int tp = wave * 8 + i;
        const bf16* wp = WoT + (size_t)(tp * 16 + lr) * 64;
        bf16x8 b0 = *(const bf16x8*)(wp + lq * 8);
        bf16x8 b1 = *(const bf16x8*)(wp + 32 + lq * 8);
        floatx4 o = {};
        o = MFMA(af0, b0, o);
        o = MFMA(af1, b1, o);
        float bb = bo[tp * 16 + lr];
        #pragma unroll
        for (int r = 0; r < 4; r++)
            orow[(size_t)(lq * 4 + r) * 512 + tp * 16 + lr] = o[r] + bb;
    }
}

extern "C" void kernel_launch(void* const* d_in, const int* in_sizes, int n_in,
                              void* d_out, int out_size, void* d_ws, size_t ws_size,
                              hipStream_t stream) {
    const float* query = (const float*)d_in[0];
    const float* value = (const float*)d_in[1];
    const float* Wi    = (const float*)d_in[2];
    const float* bi    = (const float*)d_in[3];
    const float* Wo    = (const float*)d_in[4];
    const float* bo    = (const float*)d_in[5];
    const int*   band  = (const int*)d_in[6];
    float* out = (float*)d_out;

    const int Dk = in_sizes[3];            // 64
    const int D  = in_sizes[5];            // 512
    const int S  = 4096;                   // fixed by the benchmark
    const int BS = in_sizes[0] / D;        // 16384
    const int B  = BS / S;                 // 4
    const float scale = 1.0f / sqrtf((float)Dk);

    bf16* WiT = (bf16*)d_ws;
    bf16* WoT = WiT + 32768;
    bf16* kvp = WoT + 32768;
    bf16* kvT = kvp + (size_t)BS * 64;

    prep_weights<<<16, 256, 0, stream>>>(Wi, Wo, WiT, WoT);

    proj_in_kernel<<<dim3(BS / 16), 256, 0, stream>>>(
        value, WiT, bi, kvp, kvT, D, S);

    band_attn_out_kernel<<<dim3(BS / 16), 256, 0, stream>>>(
        query, WiT, bi, kvp, kvT, band, WoT, bo, out, D, S, scale);
}

// Round 7
// 144.386 us; speedup vs baseline: 1.6464x; 1.0099x over previous
//
#include <hip/hip_runtime.h>
#include <math.h>

// ---------------------------------------------------------------------------
// SelectiveAttention, bf16-MFMA, 3-kernel pipeline:
//   prep_weights:   Wi->WiT bf16, Wo->WoT bf16 (transposed for B-frags)
//   proj_in(value): kv = value @ Wi + bi -> kvp (row-major) + kvT (transposed)
//   band_attn_out:  q-proj (own strip, fused) -> banded QK^T -> mask -> PV
//                   -> @Wo + bo -> out
// B=4, S=4096, D=512, Dk=64, band=128.
//
// R7: band kernel only —
//  - __launch_bounds__(256,4): cap VGPR at 128 so >=4 blocks/CU can overlap
//    the 4 barrier-separated phases (R2's band hit 256 VGPR, 2 blocks/CU).
//  - phase 1 rebalanced: 10 half-chunks (32 keys) split {3,3,2,2} across the
//    4 waves (was 5 full chunks {2,1,1,1} -> wave0 2x critical path).
//  - S-strip 16x88 -> 16x40 bf16: LDS 31.5 -> 25.3 KB.
// Timed loop still carries ~100us harness fill/restore (top-5 = fills).
//
// MFMA 16x16x32 bf16 layouts (m89-verified):
//   A-frag: lane l holds A[m=l&15][k=(l>>4)*8+j]  (16B contiguous)
//   B-frag: lane l holds B[k=(l>>4)*8+j][n=l&15]  (B^T storage -> 16B reads)
//   C/D:    lane l, reg r -> C[row=(l>>4)*4+r][col=l&15]
// ---------------------------------------------------------------------------

typedef __bf16 bf16;
using bf16x4  = __attribute__((ext_vector_type(4))) __bf16;
using bf16x8  = __attribute__((ext_vector_type(8))) __bf16;
using floatx4 = __attribute__((ext_vector_type(4))) float;

#define MFMA(a, b, c) __builtin_amdgcn_mfma_f32_16x16x32_bf16(a, b, c, 0, 0, 0)

// WiT[n][k]=Wi[k][n] (64x512 bf16), WoT[n][k]=Wo[k][n] (512x64 bf16).
__global__ __launch_bounds__(256) void prep_weights(
    const float* __restrict__ Wi, const float* __restrict__ Wo,
    bf16* __restrict__ WiT, bf16* __restrict__ WoT)
{
    __shared__ float T[64][65];
    const int blk = blockIdx.x, tid = threadIdx.x;
    if (blk < 8) {
        const int k0 = blk * 64;
        #pragma unroll
        for (int i = 0; i < 4; i++) {
            int idx4 = tid * 4 + i;
            int r = idx4 >> 4, c4 = (idx4 & 15) * 4;
            float4 f = *(const float4*)(Wi + (size_t)(k0 + r) * 64 + c4);
            T[r][c4 + 0] = f.x; T[r][c4 + 1] = f.y;
            T[r][c4 + 2] = f.z; T[r][c4 + 3] = f.w;
        }
        __syncthreads();
        #pragma unroll
        for (int i = 0; i < 2; i++) {
            int seg = tid * 2 + i;
            int n = seg >> 3, k8 = (seg & 7) * 8;
            bf16x8 v;
            #pragma unroll
            for (int j = 0; j < 8; j++) v[j] = (bf16)T[k8 + j][n];
            *(bf16x8*)(WiT + (size_t)n * 512 + k0 + k8) = v;
        }
    } else {
        const int n0 = (blk - 8) * 64;
        #pragma unroll
        for (int i = 0; i < 4; i++) {
            int idx4 = tid * 4 + i;
            int r = idx4 >> 4, c4 = (idx4 & 15) * 4;
            float4 f = *(const float4*)(Wo + (size_t)r * 512 + n0 + c4);
            T[r][c4 + 0] = f.x; T[r][c4 + 1] = f.y;
            T[r][c4 + 2] = f.z; T[r][c4 + 3] = f.w;
        }
        __syncthreads();
        #pragma unroll
        for (int i = 0; i < 2; i++) {
            int seg = tid * 2 + i;
            int n = seg >> 3, k8 = (seg & 7) * 8;
            bf16x8 v;
            #pragma unroll
            for (int j = 0; j < 8; j++) v[j] = (bf16)T[k8 + j][n];
            *(bf16x8*)(WoT + (size_t)(n0 + n) * 64 + k8) = v;
        }
    }
}

// One block = 16 rows of value. Wave w covers k in [w*128,(w+1)*128). LDS
// reduce -> kvp row-major + kvT[d][s] transposed.
__global__ __launch_bounds__(256, 4) void proj_in_kernel(
    const float* __restrict__ v, const bf16* __restrict__ WiT,
    const float* __restrict__ bi, bf16* __restrict__ kvp,
    bf16* __restrict__ kvT, int K, int S)
{
    __shared__ float P[4][16][68];                    // [wave][row][col]
    const int tid = threadIdx.x;
    const int wave = tid >> 6, lane = tid & 63;
    const int lr = lane & 15, lq = lane >> 4;
    const int row0 = blockIdx.x * 16;
    const float* xrow = v + (size_t)(row0 + lr) * K + wave * 128;
    const bf16* wrow = WiT + wave * 128;

    floatx4 acc[4] = {};
    #pragma unroll
    for (int ks = 0; ks < 4; ks++) {
        const int k0 = ks * 32 + lq * 8;
        float4 a0 = *(const float4*)(xrow + k0);
        float4 a1 = *(const float4*)(xrow + k0 + 4);
        bf16x8 af;
        af[0] = (bf16)a0.x; af[1] = (bf16)a0.y; af[2] = (bf16)a0.z; af[3] = (bf16)a0.w;
        af[4] = (bf16)a1.x; af[5] = (bf16)a1.y; af[6] = (bf16)a1.z; af[7] = (bf16)a1.w;
        #pragma unroll
        for (int t = 0; t < 4; t++) {
            bf16x8 bfv = *(const bf16x8*)(wrow + (size_t)(t * 16 + lr) * K + k0);
            acc[t] = MFMA(af, bfv, acc[t]);
        }
    }
    #pragma unroll
    for (int t = 0; t < 4; t++)
        #pragma unroll
        for (int r = 0; r < 4; r++)
            P[wave][lq * 4 + r][t * 16 + lr] = acc[t][r];
    __syncthreads();

    {   // reduce + row-major write
        const int row = tid >> 4, c4 = (tid & 15) * 4;
        float4 s0 = *(const float4*)&P[0][row][c4];
        float4 s1 = *(const float4*)&P[1][row][c4];
        float4 s2 = *(const float4*)&P[2][row][c4];
        float4 s3 = *(const float4*)&P[3][row][c4];
        float4 bb = *(const float4*)(bi + c4);
        bf16x4 o;
        o[0] = (bf16)(s0.x + s1.x + s2.x + s3.x + bb.x);
        o[1] = (bf16)(s0.y + s1.y + s2.y + s3.y + bb.y);
        o[2] = (bf16)(s0.z + s1.z + s2.z + s3.z + bb.z);
        o[3] = (bf16)(s0.w + s1.w + s2.w + s3.w + bb.w);
        *(bf16x4*)(kvp + (size_t)(row0 + row) * 64 + c4) = o;
    }
    {   // kvT[d][s] transpose write
        const int d = tid >> 2, s4 = (tid & 3) * 4;
        const int b = row0 >> 12, s0r = row0 & (S - 1);
        const float bb = bi[d];
        bf16x4 o;
        #pragma unroll
        for (int i = 0; i < 4; i++) {
            float s = P[0][s4 + i][d] + P[1][s4 + i][d]
                    + P[2][s4 + i][d] + P[3][s4 + i][d] + bb;
            o[i] = (bf16)s;
        }
        *(bf16x4*)(kvT + ((size_t)b * 64 + d) * S + s0r + s4) = o;
    }
}

// One block = one 16-query strip; 4 waves cooperate.
// Phase 0: fused q-proj of own strip (K-split x4, LDS reduce, +bi, *scale).
// Phase 1 (barrier-free per wave): 10 half-chunks (32 keys) split {3,3,2,2}:
//   QK^T -> mask -> private 32-wide S-strip -> PV partial acc.
// Phase 2: reduce acc via LDS -> shared bf16 att strip.
// Phase 3: each wave does 8 of 32 n-tiles of att @ Wo + bo.
__global__ __launch_bounds__(256, 4) void band_attn_out_kernel(
    const float* __restrict__ query, const bf16* __restrict__ WiT,
    const float* __restrict__ bi, const bf16* __restrict__ kvp,
    const bf16* __restrict__ kvT, const int* __restrict__ band_ptr,
    const bf16* __restrict__ WoT, const float* __restrict__ bo,
    float* __restrict__ out, int K, int S, float scale)
{
    __shared__ float P[4][16][68];                    // partials (q-proj, acc)
    __shared__ bf16 Ss[4][16][40];                    // per-wave 32-key S strip
    __shared__ bf16 St[16][88];                       // q strip / att strip
    const int tid = threadIdx.x;
    const int wave = tid >> 6, lane = tid & 63;
    const int lr = lane & 15, lq = lane >> 4;
    const int gs = blockIdx.x;                        // strip id
    const int b = gs >> 8;                            // 256 strips per batch
    const int q0 = (gs & 255) * 16;
    const int band = band_ptr[0];

    // ---- phase 0: q-proj of rows [b*S+q0, +16) ----
    {
        const float* xrow = query + ((size_t)b * S + q0 + lr) * K + wave * 128;
        const bf16* wrow = WiT + wave * 128;
        floatx4 qa[4] = {};
        #pragma unroll
        for (int ks = 0; ks < 4; ks++) {
            const int k0 = ks * 32 + lq * 8;
            float4 a0 = *(const float4*)(xrow + k0);
            float4 a1 = *(const float4*)(xrow + k0 + 4);
            bf16x8 af;
            af[0] = (bf16)a0.x; af[1] = (bf16)a0.y; af[2] = (bf16)a0.z; af[3] = (bf16)a0.w;
            af[4] = (bf16)a1.x; af[5] = (bf16)a1.y; af[6] = (bf16)a1.z; af[7] = (bf16)a1.w;
            #pragma unroll
            for (int t = 0; t < 4; t++) {
                bf16x8 bfv = *(const bf16x8*)(wrow + (size_t)(t * 16 + lr) * K + k0);
                qa[t] = MFMA(af, bfv, qa[t]);
            }
        }
        #pragma unroll
        for (int t = 0; t < 4; t++)
            #pragma unroll
            for (int r = 0; r < 4; r++)
                P[wave][lq * 4 + r][t * 16 + lr] = qa[t][r];
    }
    __syncthreads();
    {   // reduce + bias + scale -> bf16 q strip
        const int row = tid >> 4, c4 = (tid & 15) * 4;
        float4 s0 = *(const float4*)&P[0][row][c4];
        float4 s1 = *(const float4*)&P[1][row][c4];
        float4 s2 = *(const float4*)&P[2][row][c4];
        float4 s3 = *(const float4*)&P[3][row][c4];
        float4 bb = *(const float4*)(bi + c4);
        bf16x4 o;
        o[0] = (bf16)((s0.x + s1.x + s2.x + s3.x + bb.x) * scale);
        o[1] = (bf16)((s0.y + s1.y + s2.y + s3.y + bb.y) * scale);
        o[2] = (bf16)((s0.z + s1.z + s2.z + s3.z + bb.z) * scale);
        o[3] = (bf16)((s0.w + s1.w + s2.w + s3.w + bb.w) * scale);
        *(bf16x4*)(&St[row][c4]) = o;
    }
    __syncthreads();
    bf16x8 qf0 = *(const bf16x8*)(&St[lr][lq * 8]);
    bf16x8 qf1 = *(const bf16x8*)(&St[lr][32 + lq * 8]);

    // ---- phase 1: 10 half-chunks of 32 keys; wave w does {w, w+4, w+8} ----
    floatx4 acc[4] = {};
    const int base = ((q0 - band) >> 6) * 64;         // floor-div chunk base
    #pragma unroll
    for (int i = 0; i < 3; i++) {
        const int h = wave + i * 4;
        if (h < 10) {
            const int kj0 = base + h * 32;
            // QK^T for the 2 key 16-tiles of this half-chunk
            floatx4 sc[2] = {};
            #pragma unroll
            for (int t2 = 0; t2 < 2; t2++) {
                int kr = kj0 + t2 * 16 + lr;
                int krc = min(max(kr, 0), S - 1);     // clamp; masked below
                const bf16* kp = kvp + ((size_t)b * S + krc) * 64;
                bf16x8 b0 = *(const bf16x8*)(kp + lq * 8);
                bf16x8 b1 = *(const bf16x8*)(kp + 32 + lq * 8);
                sc[t2] = MFMA(qf0, b0, sc[t2]);
                sc[t2] = MFMA(qf1, b1, sc[t2]);
            }
            #pragma unroll
            for (int t2 = 0; t2 < 2; t2++) {
                int kj = kj0 + t2 * 16 + lr;
                bool kv_ok = (kj >= 0) && (kj < S);
                #pragma unroll
                for (int r = 0; r < 4; r++) {
                    int qi = q0 + lq * 4 + r;
                    int dlt = qi - kj; dlt = dlt < 0 ? -dlt : dlt;
                    float vv = (kv_ok && dlt <= band) ? sc[t2][r] : 0.f;
                    Ss[wave][lq * 4 + r][t2 * 16 + lr] = (bf16)vv;
                }
            }
            // same-wave LDS write->read: in-order per wave, no barrier needed
            bf16x8 sa = *(const bf16x8*)(&Ss[wave][lr][lq * 8]);
            int kb = kj0 + lq * 8;                    // 8-aligned segment
            int kbc = min(max(kb, 0), S - 8);         // clamp; S entries are 0
            #pragma unroll
            for (int t = 0; t < 4; t++) {
                bf16x8 vb = *(const bf16x8*)(kvT + ((size_t)b * 64 + t * 16 + lr) * S + kbc);
                acc[t] = MFMA(sa, vb, acc[t]);
            }
        }
    }
    #pragma unroll
    for (int t = 0; t < 4; t++)
        #pragma unroll
        for (int r = 0; r < 4; r++)
            P[wave][lq * 4 + r][t * 16 + lr] = acc[t][r];
    __syncthreads();

    // ---- phase 2: reduce 4 partials -> bf16 att strip ----
    {
        const int row = tid >> 4, c4 = (tid & 15) * 4;
        float4 s0 = *(const float4*)&P[0][row][c4];
        float4 s1 = *(const float4*)&P[1][row][c4];
        float4 s2 = *(const float4*)&P[2][row][c4];
        float4 s3 = *(const float4*)&P[3][row][c4];
        bf16x4 o;
        o[0] = (bf16)(s0.x + s1.x + s2.x + s3.x);
        o[1] = (bf16)(s0.y + s1.y + s2.y + s3.y);
        o[2] = (bf16)(s0.z + s1.z + s2.z + s3.z);
        o[3] = (bf16)(s0.w + s1.w + s2.w + s3.w);
        *(bf16x4*)(&St[row][c4]) = o;
    }
    __syncthreads();

    // ---- phase 3: epilogue quarter per wave: n-tiles wave*8 .. wave*8+7 ----
    bf16x8 af0 = *(const bf16x8*)(&St[lr][lq * 8]);
    bf16x8 af1 = *(const bf16x8*)(&St[lr][32 + lq * 8]);
    float* orow = out + ((size_t)b * S + q0) * 512;
    #pragma unroll
    for (int i = 0; i < 8; i++) {
        const int tp = wave * 8 + i;
        const bf16* wp = WoT + (size_t)(tp * 16 + lr) * 64;
        bf16x8 b0 = *(const bf16x8*)(wp + lq * 8);
        bf16x8 b1 = *(const bf16x8*)(wp + 32 + lq * 8);
        floatx4 o = {};
        o = MFMA(af0, b0, o);
        o = MFMA(af1, b1, o);
        float bb = bo[tp * 16 + lr];
        #pragma unroll
        for (int r = 0; r < 4; r++)
            orow[(size_t)(lq * 4 + r) * 512 + tp * 16 + lr] = o[r] + bb;
    }
}

extern "C" void kernel_launch(void* const* d_in, const int* in_sizes, int n_in,
                              void* d_out, int out_size, void* d_ws, size_t ws_size,
                              hipStream_t stream) {
    const float* query = (const float*)d_in[0];
    const float* value = (const float*)d_in[1];
    const float* Wi    = (const float*)d_in[2];
    const float* bi    = (const float*)d_in[3];
    const float* Wo    = (const float*)d_in[4];
    const float* bo    = (const float*)d_in[5];
    const int*   band  = (const int*)d_in[6];
    float* out = (float*)d_out;

    const int Dk = in_sizes[3];            // 64
    const int D  = in_sizes[5];            // 512
    const int S  = 4096;                   // fixed by the benchmark
    const int BS = in_sizes[0] / D;        // 16384
    const int B  = BS / S;                 // 4
    const float scale = 1.0f / sqrtf((float)Dk);

    bf16* WiT = (bf16*)d_ws;
    bf16* WoT = WiT + 32768;
    bf16* kvp = WoT + 32768;
    bf16* kvT = kvp + (size_t)BS * 64;

    prep_weights<<<16, 256, 0, stream>>>(Wi, Wo, WiT, WoT);

    proj_in_kernel<<<dim3(BS / 16), 256, 0, stream>>>(
        value, WiT, bi, kvp, kvT, D, S);

    band_attn_out_kernel<<<dim3(BS / 16), 256, 0, stream>>>(
        query, WiT, bi, kvp, kvT, band, WoT, bo, out, D, S, scale);
}